// Round 2
// baseline (3711.213 us; speedup 1.0000x reference)
//
#include <hip/hip_runtime.h>
#include <math.h>

#define L_SEQ 4096
#define BATCH 32
#define DM 128

__device__ __forceinline__ float gelu_f(float x) {
    return 0.5f * x * (1.0f + erff(x * 0.70710678118654752f));
}

// ---------------- conv1d embedding (circular pad 1, kernel 3) ----------------
__global__ __launch_bounds__(256) void kembed(const float* __restrict__ x,
                                              const float* __restrict__ w,
                                              float* __restrict__ h) {
    int t = blockIdx.x * 256 + threadIdx.x;          // 16.7M
    int o = t & 127; int l = (t >> 7) & 4095; int b = t >> 19;
    int lm = (l + 4095) & 4095, lp = (l + 1) & 4095;
    const float* xr0 = x + ((size_t)b * 4096 + lm) * 12;
    const float* xr1 = x + ((size_t)b * 4096 + l) * 12;
    const float* xr2 = x + ((size_t)b * 4096 + lp) * 12;
    const float* wo = w + o * 36;
    float s = 0.f;
#pragma unroll
    for (int c = 0; c < 12; c++)
        s += wo[c * 3 + 0] * xr0[c] + wo[c * 3 + 1] * xr1[c] + wo[c * 3 + 2] * xr2[c];
    h[t] = s;
}

// ---------------- f32 GEMM: C[m,n] = A[m,:] . W[n,:] + bias[n], K=128, 64x64 tile ----------------
__global__ __launch_bounds__(256) void kgemm128(const float* __restrict__ A,
                                                const float* __restrict__ W,
                                                const float* __restrict__ bias,
                                                float* __restrict__ C, int ldc) {
    __shared__ float As[64][129];
    __shared__ float Ws[64][129];
    int row0 = blockIdx.x * 64;
    int col0 = blockIdx.y * 64;
    int tid = threadIdx.x;
#pragma unroll
    for (int i = 0; i < 8; i++) {
        int e = tid + i * 256;                // 2048 float4
        int r = e >> 5; int k4 = (e & 31) * 4;
        float4 va = *(const float4*)&A[((size_t)(row0 + r)) * 128 + k4];
        As[r][k4] = va.x; As[r][k4 + 1] = va.y; As[r][k4 + 2] = va.z; As[r][k4 + 3] = va.w;
        float4 vw = *(const float4*)&W[((size_t)(col0 + r)) * 128 + k4];
        Ws[r][k4] = vw.x; Ws[r][k4 + 1] = vw.y; Ws[r][k4 + 2] = vw.z; Ws[r][k4 + 3] = vw.w;
    }
    __syncthreads();
    int tr = (tid >> 4) * 4, tc = (tid & 15) * 4;
    float acc[4][4] = {{0.f}};
    for (int k = 0; k < 128; k++) {
        float a[4], w[4];
#pragma unroll
        for (int i = 0; i < 4; i++) { a[i] = As[tr + i][k]; w[i] = Ws[tc + i][k]; }
#pragma unroll
        for (int i = 0; i < 4; i++)
#pragma unroll
            for (int j = 0; j < 4; j++) acc[i][j] += a[i] * w[j];
    }
#pragma unroll
    for (int j = 0; j < 4; j++) {
        float bj = bias[col0 + tc + j];
#pragma unroll
        for (int i = 0; i < 4; i++)
            C[(size_t)(row0 + tr + i) * ldc + col0 + tc + j] = acc[i][j] + bj;
    }
}

// ---- GEMM with transposed epilogue: CT[b][cbase+n][l] = A[b*4096+l,:].W[n,:] + bias[n], N=64 ----
__global__ __launch_bounds__(256) void kgemm128t(const float* __restrict__ A,
                                                 const float* __restrict__ W,
                                                 const float* __restrict__ bias,
                                                 float* __restrict__ CT, int cbase) {
    __shared__ float As[64][129];
    __shared__ float Ws[64][129];
    int row0 = blockIdx.x * 64;
    int tid = threadIdx.x;
#pragma unroll
    for (int i = 0; i < 8; i++) {
        int e = tid + i * 256;
        int r = e >> 5; int k4 = (e & 31) * 4;
        float4 va = *(const float4*)&A[((size_t)(row0 + r)) * 128 + k4];
        As[r][k4] = va.x; As[r][k4 + 1] = va.y; As[r][k4 + 2] = va.z; As[r][k4 + 3] = va.w;
        if (i < 8) {
            float4 vw = *(const float4*)&W[((size_t)r) * 128 + k4];
            Ws[r][k4] = vw.x; Ws[r][k4 + 1] = vw.y; Ws[r][k4 + 2] = vw.z; Ws[r][k4 + 3] = vw.w;
        }
    }
    __syncthreads();
    int tr = (tid >> 4) * 4, tc = (tid & 15) * 4;
    float acc[4][4] = {{0.f}};
    for (int k = 0; k < 128; k++) {
        float a[4], w[4];
#pragma unroll
        for (int i = 0; i < 4; i++) { a[i] = As[tr + i][k]; w[i] = Ws[tc + i][k]; }
#pragma unroll
        for (int i = 0; i < 4; i++)
#pragma unroll
            for (int j = 0; j < 4; j++) acc[i][j] += a[i] * w[j];
    }
    int b = row0 >> 12;
    int l0 = (row0 & 4095) + tr;
#pragma unroll
    for (int j = 0; j < 4; j++) {
        float bj = bias[tc + j];
        float* dst = CT + ((size_t)(b * 128 + cbase + tc + j)) * 4096 + l0;
        *(float4*)dst = make_float4(acc[0][j] + bj, acc[1][j] + bj, acc[2][j] + bj, acc[3][j] + bj);
    }
}

// ---------------- Stockham FFT length 4096 in LDS (256 threads), LDS twiddle table ----------------
__device__ void fft4096(float2* __restrict__ bufA, float2* __restrict__ bufB,
                        const float2* __restrict__ tw, float sgn) {
    float2* cur = bufA; float2* nxt = bufB;
#pragma unroll 1
    for (int t = 0; t < 12; t++) {
        int s = 1 << t;
#pragma unroll
        for (int ii = 0; ii < 8; ii++) {
            int idx = threadIdx.x + (ii << 8);
            int p = idx >> t;
            int q = idx & (s - 1);
            int ia = q + (p << t);
            float2 a = cur[ia];
            float2 b = cur[ia + 2048];
            float2 w = tw[p << t];
            float cs = w.x, sn = w.y * sgn;
            float dx = a.x - b.x, dy = a.y - b.y;
            int ob = q + (p << (t + 1));
            nxt[ob] = make_float2(a.x + b.x, a.y + b.y);
            nxt[ob + s] = make_float2(dx * cs - dy * sn, dx * sn + dy * cs);
        }
        __syncthreads();
        float2* tmpp = cur; cur = nxt; nxt = tmpp;
    }
}

// Packed FFT of (q + i k) per (b, channel); accumulate P = Q conj(K) over 8 channels.
// qkT layout: [b][128][4096], cols 0..63 = q channels (this half), 64..127 = k channels.
__global__ __launch_bounds__(256) void kfft_fwd(const float* __restrict__ qkT,
                                                float* __restrict__ Pws, int ghalf) {
    __shared__ float2 bufA[4096];
    __shared__ float2 bufB[4096];
    __shared__ float2 tw[2048];
    for (int j = threadIdx.x; j < 2048; j += 256) {
        float sn, cs;
        sincosf(1.5339807878856412e-3f * (float)j, &sn, &cs);   // 2*pi/4096 * j
        tw[j] = make_float2(cs, sn);
    }
    int b = blockIdx.x >> 3;
    int gl = blockIdx.x & 7;
    float2 pacc[16];
#pragma unroll
    for (int j = 0; j < 16; j++) pacc[j] = make_float2(0.f, 0.f);
    for (int c8 = 0; c8 < 8; c8++) {
        int c = gl * 8 + c8;
        const float* qrow = qkT + ((size_t)(b * 128 + c)) * 4096;
        const float* krow = qkT + ((size_t)(b * 128 + 64 + c)) * 4096;
        for (int i = threadIdx.x; i < 4096; i += 256)
            bufA[i] = make_float2(qrow[i], krow[i]);
        __syncthreads();
        fft4096(bufA, bufB, tw, -1.f);
#pragma unroll
        for (int j = 0; j < 16; j++) {
            int f = threadIdx.x + j * 256;
            float2 Zf = bufA[f];
            float2 Zm = bufA[(4096 - f) & 4095];
            float Qre = 0.5f * (Zf.x + Zm.x), Qim = 0.5f * (Zf.y - Zm.y);
            float Kre = 0.5f * (Zf.y + Zm.y), Kim = -0.5f * (Zf.x - Zm.x);
            pacc[j].x += Qre * Kre + Qim * Kim;
            pacc[j].y += Qim * Kre - Qre * Kim;
        }
        __syncthreads();
    }
    float2* P = (float2*)Pws + (size_t)(b * 16 + ghalf * 8 + gl) * 4096;
#pragma unroll
    for (int j = 0; j < 16; j++) { int f = threadIdx.x + j * 256; P[f] = pacc[j]; }
}

__global__ __launch_bounds__(256) void kfft_inv(const float* __restrict__ Pws,
                                                float* __restrict__ meanv) {
    __shared__ float2 bufA[4096];
    __shared__ float2 bufB[4096];
    __shared__ float2 tw[2048];
    for (int j = threadIdx.x; j < 2048; j += 256) {
        float sn, cs;
        sincosf(1.5339807878856412e-3f * (float)j, &sn, &cs);
        tw[j] = make_float2(cs, sn);
    }
    int b = blockIdx.x;
    const float2* P = (const float2*)Pws + (size_t)b * 16 * 4096;
    for (int i = threadIdx.x; i < 4096; i += 256) {
        float2 s = make_float2(0.f, 0.f);
#pragma unroll
        for (int gg = 0; gg < 16; gg++) { float2 v = P[gg * 4096 + i]; s.x += v.x; s.y += v.y; }
        bufA[i] = s;
    }
    __syncthreads();
    fft4096(bufA, bufB, tw, 1.f);
    const float scale = 1.0f / (4096.0f * 128.0f);
    for (int i = threadIdx.x; i < 4096; i += 256)
        meanv[b * 4096 + i] = bufA[i].x * scale;
}

// ---------------- top-8 over batch-sum + per-batch softmax weights ----------------
__global__ __launch_bounds__(256) void ktopk(const float* __restrict__ meanv,
                                             int* __restrict__ idxout,
                                             float* __restrict__ tc) {
    __shared__ float cm[4096];
    __shared__ float rv[256];
    __shared__ int ri[256];
    __shared__ int sidx[8];
    for (int c = threadIdx.x; c < 4096; c += 256) {
        float s = 0.f;
        for (int b = 0; b < 32; b++) s += meanv[b * 4096 + c];
        cm[c] = s;
    }
    __syncthreads();
    for (int it = 0; it < 8; it++) {
        float bv = -1e30f; int bi = 0;
        for (int c = threadIdx.x; c < 4096; c += 256) {
            float v = cm[c];
            if (v > bv || (v == bv && c < bi)) { bv = v; bi = c; }
        }
        rv[threadIdx.x] = bv; ri[threadIdx.x] = bi;
        __syncthreads();
        for (int off = 128; off > 0; off >>= 1) {
            if (threadIdx.x < off) {
                float v2 = rv[threadIdx.x + off]; int i2 = ri[threadIdx.x + off];
                if (v2 > rv[threadIdx.x] || (v2 == rv[threadIdx.x] && i2 < ri[threadIdx.x])) {
                    rv[threadIdx.x] = v2; ri[threadIdx.x] = i2;
                }
            }
            __syncthreads();
        }
        if (threadIdx.x == 0) { sidx[it] = ri[0]; idxout[it] = ri[0]; cm[ri[0]] = -1e30f; }
        __syncthreads();
    }
    if (threadIdx.x < 32) {
        int b = threadIdx.x;
        float w[8]; float mx = -1e30f;
#pragma unroll
        for (int i = 0; i < 8; i++) { w[i] = meanv[b * 4096 + sidx[i]]; mx = fmaxf(mx, w[i]); }
        float s = 0.f;
#pragma unroll
        for (int i = 0; i < 8; i++) { w[i] = expf(w[i] - mx); s += w[i]; }
#pragma unroll
        for (int i = 0; i < 8; i++) tc[b * 8 + i] = w[i] / s;
    }
}

// ---- fused aggregation + o-proj + residual, X updated in place over h ----
// X[b*4096+l, n] += bias[n] + sum_k (sum_i tc_i * v[b*4096 + (l+idx_i)%L, k]) * W[n,k]
__global__ __launch_bounds__(256) void kaggoproj(const float* __restrict__ v,
                                                 const float* __restrict__ W,
                                                 const float* __restrict__ bias,
                                                 const float* __restrict__ tcb,
                                                 const int* __restrict__ idxb,
                                                 float* __restrict__ X) {
    __shared__ float As[64][129];
    __shared__ float Ws[64][129];
    int row0 = blockIdx.x * 64;
    int col0 = blockIdx.y * 64;
    int b = row0 >> 12;
    int l0 = row0 & 4095;
    int tid = threadIdx.x;
    // stage W tile
#pragma unroll
    for (int i = 0; i < 8; i++) {
        int e = tid + i * 256; int r = e >> 5; int k4 = (e & 31) * 4;
        float4 vw = *(const float4*)&W[((size_t)(col0 + r)) * 128 + k4];
        Ws[r][k4] = vw.x; Ws[r][k4 + 1] = vw.y; Ws[r][k4 + 2] = vw.z; Ws[r][k4 + 3] = vw.w;
    }
    // build aggregated A tile in registers
    float4 av[8];
#pragma unroll
    for (int u = 0; u < 8; u++) av[u] = make_float4(0.f, 0.f, 0.f, 0.f);
    for (int i = 0; i < 8; i++) {
        float wgt = tcb[b * 8 + i];
        int off = idxb[i];
#pragma unroll
        for (int u = 0; u < 8; u++) {
            int e = tid + u * 256; int r = e >> 5; int k4 = (e & 31) * 4;
            int lr = (l0 + r + off) & 4095;
            float4 vv = *(const float4*)&v[((size_t)(b * 4096 + lr)) * 128 + k4];
            av[u].x += wgt * vv.x; av[u].y += wgt * vv.y;
            av[u].z += wgt * vv.z; av[u].w += wgt * vv.w;
        }
    }
#pragma unroll
    for (int u = 0; u < 8; u++) {
        int e = tid + u * 256; int r = e >> 5; int k4 = (e & 31) * 4;
        As[r][k4] = av[u].x; As[r][k4 + 1] = av[u].y; As[r][k4 + 2] = av[u].z; As[r][k4 + 3] = av[u].w;
    }
    __syncthreads();
    int tr = (tid >> 4) * 4, tc = (tid & 15) * 4;
    float acc[4][4] = {{0.f}};
    for (int k = 0; k < 128; k++) {
        float a[4], w[4];
#pragma unroll
        for (int i = 0; i < 4; i++) { a[i] = As[tr + i][k]; w[i] = Ws[tc + i][k]; }
#pragma unroll
        for (int i = 0; i < 4; i++)
#pragma unroll
            for (int j = 0; j < 4; j++) acc[i][j] += a[i] * w[j];
    }
#pragma unroll
    for (int j = 0; j < 4; j++) {
        float bj = bias[col0 + tc + j];
#pragma unroll
        for (int i = 0; i < 4; i++) {
            size_t o = (size_t)(row0 + tr + i) * 128 + col0 + tc + j;
            X[o] = X[o] + acc[i][j] + bj;
        }
    }
}

// ---------------- series decomp: out = in - movavg25(in), replicate pad ----------------
__global__ __launch_bounds__(256) void kdecomp(const float* __restrict__ in,
                                               float* __restrict__ out) {
    int t = blockIdx.x * 256 + threadIdx.x;
    int l = (t >> 7) & 4095; int b = t >> 19;
    const float* base = in + ((size_t)b * 4096) * 128 + (t & 127);
    float s = 0.f;
#pragma unroll
    for (int j = -12; j <= 12; j++) {
        int lj = l + j;
        lj = lj < 0 ? 0 : (lj > 4095 ? 4095 : lj);
        s += base[(size_t)lj * 128];
    }
    out[t] = in[t] - s * (1.0f / 25.0f);
}

// ---------------- fused FFN: out = xs + gelu(xs@w1^T)@w2^T, M-tile 128 ----------------
__global__ __launch_bounds__(256) void kffn(const float* __restrict__ xs,
                                            const float* __restrict__ w1,
                                            const float* __restrict__ w2,
                                            float* __restrict__ out) {
    __shared__ float xsl[128][129];
    __shared__ float w1l[32][129];
    __shared__ float w2l[32][128];
    __shared__ float tl[128][33];
    int row0 = blockIdx.x * 128;
    int tid = threadIdx.x;
#pragma unroll
    for (int i = 0; i < 16; i++) {
        int e = tid + i * 256; int r = e >> 5; int k4 = (e & 31) * 4;
        float4 v = *(const float4*)&xs[(size_t)(row0 + r) * 128 + k4];
        xsl[r][k4] = v.x; xsl[r][k4 + 1] = v.y; xsl[r][k4 + 2] = v.z; xsl[r][k4 + 3] = v.w;
    }
    float acc2[4][16];
#pragma unroll
    for (int i = 0; i < 4; i++)
#pragma unroll
        for (int j = 0; j < 16; j++) acc2[i][j] = 0.f;
    int r1 = (tid >> 3) * 4, f1 = (tid & 7) * 4;
    int d0 = (tid & 7) * 16;
    __syncthreads();
    for (int fb = 0; fb < 512; fb += 32) {
#pragma unroll
        for (int i = 0; i < 4; i++) {
            int e = tid + i * 256; int fr = e >> 5; int k4 = (e & 31) * 4;
            float4 v = *(const float4*)&w1[(size_t)(fb + fr) * 128 + k4];
            w1l[fr][k4] = v.x; w1l[fr][k4 + 1] = v.y; w1l[fr][k4 + 2] = v.z; w1l[fr][k4 + 3] = v.w;
        }
#pragma unroll
        for (int i = 0; i < 16; i++) {
            int e = tid + i * 256; int d = e >> 5, f = e & 31;
            w2l[f][d] = w2[(size_t)d * 512 + fb + f];
        }
        __syncthreads();
        // stage 1: tl[128][32] = gelu(xsl @ w1l^T)
        float a[4][4];
#pragma unroll
        for (int i = 0; i < 4; i++)
#pragma unroll
            for (int j = 0; j < 4; j++) a[i][j] = 0.f;
        for (int k = 0; k < 128; k++) {
            float x0 = xsl[r1][k], x1 = xsl[r1 + 1][k], x2 = xsl[r1 + 2][k], x3 = xsl[r1 + 3][k];
            float b0 = w1l[f1][k], b1 = w1l[f1 + 1][k], b2 = w1l[f1 + 2][k], b3 = w1l[f1 + 3][k];
            a[0][0] += x0 * b0; a[0][1] += x0 * b1; a[0][2] += x0 * b2; a[0][3] += x0 * b3;
            a[1][0] += x1 * b0; a[1][1] += x1 * b1; a[1][2] += x1 * b2; a[1][3] += x1 * b3;
            a[2][0] += x2 * b0; a[2][1] += x2 * b1; a[2][2] += x2 * b2; a[2][3] += x2 * b3;
            a[3][0] += x3 * b0; a[3][1] += x3 * b1; a[3][2] += x3 * b2; a[3][3] += x3 * b3;
        }
#pragma unroll
        for (int i = 0; i < 4; i++)
#pragma unroll
            for (int j = 0; j < 4; j++) tl[r1 + i][f1 + j] = gelu_f(a[i][j]);
        __syncthreads();
        // stage 2: acc2[4][16] += tl @ w2l
        for (int f = 0; f < 32; f++) {
            float t0 = tl[r1][f], t1 = tl[r1 + 1][f], t2 = tl[r1 + 2][f], t3 = tl[r1 + 3][f];
#pragma unroll
            for (int jj = 0; jj < 16; jj++) {
                float wv = w2l[f][d0 + jj];
                acc2[0][jj] += t0 * wv; acc2[1][jj] += t1 * wv;
                acc2[2][jj] += t2 * wv; acc2[3][jj] += t3 * wv;
            }
        }
        __syncthreads();
    }
#pragma unroll
    for (int i = 0; i < 4; i++)
#pragma unroll
        for (int jj = 0; jj < 16; jj++)
            out[(size_t)(row0 + r1 + i) * 128 + d0 + jj] = xsl[r1 + i][d0 + jj] + acc2[i][jj];
}

// ---------------- layernorm over d (in place) ----------------
__global__ __launch_bounds__(256) void kln(float* __restrict__ h,
                                           const float* __restrict__ g,
                                           const float* __restrict__ bb) {
    int wave = threadIdx.x >> 6; int lane = threadIdx.x & 63;
    size_t row = (size_t)blockIdx.x * 4 + wave;
    float* p = h + row * 128;
    float v0 = p[lane], v1 = p[lane + 64];
    float s = v0 + v1, s2 = v0 * v0 + v1 * v1;
#pragma unroll
    for (int off = 32; off; off >>= 1) { s += __shfl_down(s, off); s2 += __shfl_down(s2, off); }
    s = __shfl(s, 0); s2 = __shfl(s2, 0);
    float mu = s * (1.f / 128.f);
    float var = s2 * (1.f / 128.f) - mu * mu;
    float inv = rsqrtf(var + 1e-5f);
    p[lane] = (v0 - mu) * inv * g[lane] + bb[lane];
    p[lane + 64] = (v1 - mu) * inv * g[lane + 64] + bb[lane + 64];
}

// column-sum partials: part[(b*8+s)*128+d] = sum over 512 rows
__global__ __launch_bounds__(256) void kpart1(const float* __restrict__ h,
                                              float* __restrict__ part) {
    int b = blockIdx.x >> 3, sl = blockIdx.x & 7;
    int d = threadIdx.x & 127, p = threadIdx.x >> 7;
    const float* base = h + ((size_t)b * 4096 + sl * 512) * 128;
    float acc = 0.f;
    for (int l = p; l < 512; l += 2) acc += base[(size_t)l * 128 + d];
    __shared__ float sh[256];
    sh[threadIdx.x] = acc; __syncthreads();
    if (p == 0) part[(size_t)(b * 8 + sl) * 128 + d] = acc + sh[128 + d];
}

__global__ __launch_bounds__(128) void kpart2(const float* __restrict__ part,
                                              float* __restrict__ outm) {
    int b = blockIdx.x; int d = threadIdx.x;
    float s = 0.f;
#pragma unroll
    for (int q = 0; q < 8; q++) s += part[(size_t)(b * 8 + q) * 128 + d];
    outm[b * 128 + d] = s * (1.f / 4096.f);
}

// gelu(h - colmean) partials
__global__ __launch_bounds__(256) void kgpart1(const float* __restrict__ h,
                                               const float* __restrict__ msum,
                                               float* __restrict__ part) {
    int b = blockIdx.x >> 3, sl = blockIdx.x & 7;
    int d = threadIdx.x & 127, p = threadIdx.x >> 7;
    const float* base = h + ((size_t)b * 4096 + sl * 512) * 128;
    float m = msum[b * 128 + d];
    float acc = 0.f;
    for (int l = p; l < 512; l += 2) acc += gelu_f(base[(size_t)l * 128 + d] - m);
    __shared__ float sh[256];
    sh[threadIdx.x] = acc; __syncthreads();
    if (p == 0) part[(size_t)(b * 8 + sl) * 128 + d] = acc + sh[128 + d];
}

__global__ __launch_bounds__(256) void khead(const float* __restrict__ gmean,
                                             const float* __restrict__ fc1w,
                                             const float* __restrict__ fc1b,
                                             const float* __restrict__ fc2w,
                                             const float* __restrict__ fc2b,
                                             float* __restrict__ outp) {
    __shared__ float h0[32][128];
    __shared__ float h1[32][128];
    int tid = threadIdx.x;
#pragma unroll
    for (int i = 0; i < 16; i++) {
        int e = tid + i * 256;
        h0[e >> 7][e & 127] = gmean[e];
    }
    __syncthreads();
#pragma unroll
    for (int i = 0; i < 16; i++) {
        int e = tid + i * 256; int b = e >> 7, j = e & 127;
        float s = fc1b[j];
        for (int d = 0; d < 128; d++) s += h0[b][d] * fc1w[j * 128 + d];
        h1[b][j] = fmaxf(s, 0.f);
    }
    __syncthreads();
    if (tid < 160) {
        int b = tid / 5, c2 = tid % 5;
        float s = fc2b[c2];
        for (int j = 0; j < 128; j++) s += h1[b][j] * fc2w[c2 * 128 + j];
        outp[b * 5 + c2] = s;
    }
}

extern "C" void kernel_launch(void* const* d_in, const int* in_sizes, int n_in,
                              void* d_out, int out_size, void* d_ws, size_t ws_size,
                              hipStream_t stream) {
    const float* x_enc  = (const float*)d_in[0];
    const float* emb_w  = (const float*)d_in[1];
    const float* attn_w = (const float*)d_in[2];
    const float* attn_b = (const float*)d_in[3];
    const float* ffn_w1 = (const float*)d_in[4];
    const float* ffn_w2 = (const float*)d_in[5];
    const float* norm_g = (const float*)d_in[6];
    const float* norm_b = (const float*)d_in[7];
    const float* fc1_w  = (const float*)d_in[8];
    const float* fc1_b  = (const float*)d_in[9];
    const float* fc2_w  = (const float*)d_in[10];
    const float* fc2_b  = (const float*)d_in[11];
    float* outp = (float*)d_out;

    // workspace: 2*RD + 4,194,304 + 131,072 + 256 + 64 + 32,768 + 4,096 + 4,096 floats ~= 152 MB
    float* W = (float*)d_ws;
    const size_t RD = (size_t)BATCH * L_SEQ * DM;       // 16,777,216
    float* buf0  = W;
    float* buf1  = W + RD;
    float* Pws   = W + 2 * RD;                          // 4,194,304
    float* meanv = Pws + (size_t)4194304;               // 131,072
    float* tcb   = meanv + (size_t)131072;              // 256
    int*   idxb  = (int*)(tcb + 256);                   // 64 slots
    float* part  = tcb + 256 + 64;                      // 32,768
    float* msum  = part + 32768;                        // 4,096 (col means)
    float* gsum  = msum + 4096;                         // 4,096 (gelu means)

    kembed<<<65536, 256, 0, stream>>>(x_enc, emb_w, buf0);

    float* H = buf0;
    float* S = buf1;
    for (int l = 0; l < 2; l++) {
        const float* aw = attn_w + (size_t)l * 4 * 128 * 128;
        const float* ab = attn_b + (size_t)l * 4 * 128;
        for (int half = 0; half < 2; half++) {
            kgemm128t<<<2048, 256, 0, stream>>>(H, aw + half * 64 * 128, ab + half * 64, S, 0);
            kgemm128t<<<2048, 256, 0, stream>>>(H, aw + 128 * 128 + half * 64 * 128,
                                                ab + 128 + half * 64, S, 64);
            kfft_fwd<<<256, 256, 0, stream>>>(S, Pws, half);
        }
        kfft_inv<<<32, 256, 0, stream>>>(Pws, meanv);
        ktopk<<<1, 256, 0, stream>>>(meanv, idxb, tcb);
        // v projection
        kgemm128<<<dim3(2048, 2), 256, 0, stream>>>(H, aw + 2 * 128 * 128, ab + 256, S, 128);
        // fused agg + o-proj + residual (X in place over H)
        kaggoproj<<<dim3(2048, 2), 256, 0, stream>>>(S, aw + 3 * 128 * 128, ab + 384, tcb, idxb, H);
        // xs = X - movavg(X)
        kdecomp<<<65536, 256, 0, stream>>>(H, S);
        // t2 = xs + ffn(xs)
        kffn<<<1024, 256, 0, stream>>>(S, ffn_w1 + (size_t)l * 512 * 128,
                                       ffn_w2 + (size_t)l * 128 * 512, H);
        // h' = t2 - movavg(t2)
        kdecomp<<<65536, 256, 0, stream>>>(H, S);
        float* t = H; H = S; S = t;
    }

    kln<<<32768, 256, 0, stream>>>(H, norm_g, norm_b);
    kpart1<<<256, 256, 0, stream>>>(H, part);
    kpart2<<<32, 128, 0, stream>>>(part, msum);
    kgpart1<<<256, 256, 0, stream>>>(H, msum, part);
    kpart2<<<32, 128, 0, stream>>>(part, gsum);
    khead<<<1, 256, 0, stream>>>(gsum, fc1_w, fc1_b, fc2_w, fc2_b, outp);
}

// Round 3
// 1987.626 us; speedup vs baseline: 1.8672x; 1.8672x over previous
//
#include <hip/hip_runtime.h>
#include <math.h>

#define L_SEQ 4096
#define BATCH 32
#define DM 128

typedef short short8 __attribute__((ext_vector_type(8)));
typedef float f32x4 __attribute__((ext_vector_type(4)));

__device__ __forceinline__ float gelu_f(float x) {
    return 0.5f * x * (1.0f + erff(x * 0.70710678118654752f));
}

// exact-erf gelu via Maclaurin poly (|x|<1 -> err <2e-6), erff fallback
__device__ __forceinline__ float gelu_fast(float x) {
    float ax = fabsf(x);
    if (ax < 1.0f) {
        float z = x * 0.70710678118654752f;
        float z2 = z * z;
        float p = 1.0f + z2 * (-0.333333333f + z2 * (0.1f + z2 * (-0.0238095238f +
                  z2 * (4.62962963e-3f + z2 * (-7.57575758e-4f)))));
        return 0.5f * x * (1.0f + 1.1283791670955126f * z * p);
    }
    return 0.5f * x * (1.0f + erff(x * 0.70710678118654752f));
}

__device__ __forceinline__ unsigned short f2b(float f) {
    unsigned u = __float_as_uint(f);
    u += 0x7fffu + ((u >> 16) & 1u);
    return (unsigned short)(u >> 16);
}
__device__ __forceinline__ float b2f(unsigned short h) {
    return __uint_as_float(((unsigned)h) << 16);
}

// ---------------- conv1d embedding (circular pad 1, kernel 3) ----------------
__global__ __launch_bounds__(256) void kembed(const float* __restrict__ x,
                                              const float* __restrict__ w,
                                              float* __restrict__ h) {
    int t = blockIdx.x * 256 + threadIdx.x;
    int o = t & 127; int l = (t >> 7) & 4095; int b = t >> 19;
    int lm = (l + 4095) & 4095, lp = (l + 1) & 4095;
    const float* xr0 = x + ((size_t)b * 4096 + lm) * 12;
    const float* xr1 = x + ((size_t)b * 4096 + l) * 12;
    const float* xr2 = x + ((size_t)b * 4096 + lp) * 12;
    const float* wo = w + o * 36;
    float s = 0.f;
#pragma unroll
    for (int c = 0; c < 12; c++)
        s += wo[c * 3 + 0] * xr0[c] + wo[c * 3 + 1] * xr1[c] + wo[c * 3 + 2] * xr2[c];
    h[t] = s;
}

// ---- f32 GEMM, transposed epilogue, merged q|k: CT[b][y*64+n][l], y=blockIdx.y ----
__global__ __launch_bounds__(256) void kgemm_qkt(const float* __restrict__ A,
                                                 const float* __restrict__ aw,
                                                 const float* __restrict__ ab,
                                                 int half, float* __restrict__ CT) {
    __shared__ float As[64][129];
    __shared__ float Ws[64][129];
    int y = blockIdx.y;                       // 0 = q, 1 = k
    const float* W = aw + (size_t)y * 128 * 128 + (size_t)half * 64 * 128;
    const float* bias = ab + y * 128 + half * 64;
    int cbase = y * 64;
    int row0 = blockIdx.x * 64;
    int tid = threadIdx.x;
#pragma unroll
    for (int i = 0; i < 8; i++) {
        int e = tid + i * 256;
        int r = e >> 5; int k4 = (e & 31) * 4;
        float4 va = *(const float4*)&A[((size_t)(row0 + r)) * 128 + k4];
        As[r][k4] = va.x; As[r][k4 + 1] = va.y; As[r][k4 + 2] = va.z; As[r][k4 + 3] = va.w;
        float4 vw = *(const float4*)&W[((size_t)r) * 128 + k4];
        Ws[r][k4] = vw.x; Ws[r][k4 + 1] = vw.y; Ws[r][k4 + 2] = vw.z; Ws[r][k4 + 3] = vw.w;
    }
    __syncthreads();
    int tr = (tid >> 4) * 4, tc = (tid & 15) * 4;
    float acc[4][4] = {{0.f}};
    for (int k = 0; k < 128; k++) {
        float a[4], w[4];
#pragma unroll
        for (int i = 0; i < 4; i++) { a[i] = As[tr + i][k]; w[i] = Ws[tc + i][k]; }
#pragma unroll
        for (int i = 0; i < 4; i++)
#pragma unroll
            for (int j = 0; j < 4; j++) acc[i][j] += a[i] * w[j];
    }
    int b = row0 >> 12;
    int l0 = (row0 & 4095) + tr;
#pragma unroll
    for (int j = 0; j < 4; j++) {
        float bj = bias[tc + j];
        float* dst = CT + ((size_t)(b * 128 + cbase + tc + j)) * 4096 + l0;
        *(float4*)dst = make_float4(acc[0][j] + bj, acc[1][j] + bj, acc[2][j] + bj, acc[3][j] + bj);
    }
}

// ---------------- MFMA bf16 GEMM: C[M x 128] = A[M x 128] . W^T + bias ----------------
// AT: 0 = A is f32, 1 = A is bf16.  EPI: 0 = bf16 out, 1 = f32 out with residual add.
template <int AT, int EPI>
__global__ __launch_bounds__(256, 2) void kgemm_mfma(const void* __restrict__ Ap,
                                                     const float* __restrict__ Wf,
                                                     const float* __restrict__ bias,
                                                     const float* __restrict__ res,
                                                     void* __restrict__ outp) {
    __shared__ __align__(16) char smem[65536];
    short* As = (short*)smem;            // [128][128] bf16, swizzled
    short* Ws = (short*)(smem + 32768);  // [128][128] bf16, swizzled
    int tid = threadIdx.x;
    size_t row0 = (size_t)blockIdx.x * 128;
#pragma unroll
    for (int u = 0; u < 8; u++) {
        int g = tid + u * 256;
        int r = g >> 4, cg = g & 15;
        int dsti = r * 128 + ((cg ^ (r & 7)) << 3);
        short8 v;
        if (AT == 0) {
            const float* src = (const float*)Ap + (row0 + r) * 128 + cg * 8;
            float4 x = *(const float4*)src, y = *(const float4*)(src + 4);
            v[0] = f2b(x.x); v[1] = f2b(x.y); v[2] = f2b(x.z); v[3] = f2b(x.w);
            v[4] = f2b(y.x); v[5] = f2b(y.y); v[6] = f2b(y.z); v[7] = f2b(y.w);
        } else {
            v = *(const short8*)((const short*)Ap + (row0 + r) * 128 + cg * 8);
        }
        *(short8*)(As + dsti) = v;
        const float* ws = Wf + (size_t)r * 128 + cg * 8;
        float4 wx = *(const float4*)ws, wy = *(const float4*)(ws + 4);
        short8 wv;
        wv[0] = f2b(wx.x); wv[1] = f2b(wx.y); wv[2] = f2b(wx.z); wv[3] = f2b(wx.w);
        wv[4] = f2b(wy.x); wv[5] = f2b(wy.y); wv[6] = f2b(wy.z); wv[7] = f2b(wy.w);
        *(short8*)(Ws + dsti) = wv;
    }
    __syncthreads();
    int l = tid & 63; int w = tid >> 6; int wm = w >> 1, wn = w & 1;
    f32x4 acc[4][4];
#pragma unroll
    for (int i = 0; i < 4; i++)
#pragma unroll
        for (int j = 0; j < 4; j++) acc[i][j] = (f32x4){0.f, 0.f, 0.f, 0.f};
#pragma unroll
    for (int ks = 0; ks < 4; ks++) {
        int cg = ks * 4 + (l >> 4);
        short8 af[4], bf[4];
#pragma unroll
        for (int mi = 0; mi < 4; mi++) {
            int rm = wm * 64 + mi * 16 + (l & 15);
            af[mi] = *(short8*)(As + rm * 128 + ((cg ^ (rm & 7)) << 3));
        }
#pragma unroll
        for (int ni = 0; ni < 4; ni++) {
            int rn = wn * 64 + ni * 16 + (l & 15);
            bf[ni] = *(short8*)(Ws + rn * 128 + ((cg ^ (rn & 7)) << 3));
        }
#pragma unroll
        for (int mi = 0; mi < 4; mi++)
#pragma unroll
            for (int ni = 0; ni < 4; ni++)
                acc[mi][ni] = __builtin_amdgcn_mfma_f32_16x16x32_bf16(af[mi], bf[ni], acc[mi][ni], 0, 0, 0);
    }
    __syncthreads();
    float* Dsh = (float*)smem;           // [128][128] f32
#pragma unroll
    for (int mi = 0; mi < 4; mi++)
#pragma unroll
        for (int ni = 0; ni < 4; ni++)
#pragma unroll
            for (int rr = 0; rr < 4; rr++)
                Dsh[(wm * 64 + mi * 16 + (l >> 4) * 4 + rr) * 128 + wn * 64 + ni * 16 + (l & 15)] = acc[mi][ni][rr];
    __syncthreads();
#pragma unroll
    for (int u = 0; u < 8; u++) {
        int g = tid + u * 256;
        int r = g >> 4, c8 = (g & 15) * 8;
        float vv[8];
#pragma unroll
        for (int j = 0; j < 8; j++) vv[j] = Dsh[r * 128 + c8 + j] + bias[c8 + j];
        if (EPI == 1) {
            const float* rp = res + (row0 + r) * 128 + c8;
#pragma unroll
            for (int j = 0; j < 8; j++) vv[j] += rp[j];
            float* op = (float*)outp + (row0 + r) * 128 + c8;
            *(float4*)op = make_float4(vv[0], vv[1], vv[2], vv[3]);
            *(float4*)(op + 4) = make_float4(vv[4], vv[5], vv[6], vv[7]);
        } else {
            short8 ov;
#pragma unroll
            for (int j = 0; j < 8; j++) ov[j] = (short)f2b(vv[j]);
            *(short8*)((short*)outp + (row0 + r) * 128 + c8) = ov;
        }
    }
}

// ---------------- fused MFMA FFN: out = xs + gelu(xs@w1^T)@w2^T ----------------
__global__ __launch_bounds__(256, 1) void kffn_mfma(const float* __restrict__ xs,
                                                    const float* __restrict__ w1,
                                                    const float* __restrict__ w2,
                                                    float* __restrict__ outp) {
    __shared__ __align__(16) char smem[131072];
    short* xsl = (short*)smem;               // [128][128]
    short* w1t = (short*)(smem + 32768);     // [128][128]
    short* tt  = (short*)(smem + 65536);     // [128][128]
    short* w2t = (short*)(smem + 98304);     // [128][128]
    int tid = threadIdx.x;
    size_t row0 = (size_t)blockIdx.x * 128;
    // stage xs (f32 -> bf16, swizzled)
#pragma unroll
    for (int u = 0; u < 8; u++) {
        int g = tid + u * 256;
        int r = g >> 4, cg = g & 15;
        const float* src = xs + (row0 + r) * 128 + cg * 8;
        float4 x = *(const float4*)src, y = *(const float4*)(src + 4);
        short8 v;
        v[0] = f2b(x.x); v[1] = f2b(x.y); v[2] = f2b(x.z); v[3] = f2b(x.w);
        v[4] = f2b(y.x); v[5] = f2b(y.y); v[6] = f2b(y.z); v[7] = f2b(y.w);
        *(short8*)(xsl + r * 128 + ((cg ^ (r & 7)) << 3)) = v;
    }
    int l = tid & 63; int w = tid >> 6; int wm = w >> 1, wn = w & 1;
    f32x4 acc2[4][4];
#pragma unroll
    for (int i = 0; i < 4; i++)
#pragma unroll
        for (int j = 0; j < 4; j++) acc2[i][j] = (f32x4){0.f, 0.f, 0.f, 0.f};
    for (int fb = 0; fb < 4; fb++) {
        __syncthreads();   // protect w1t/w2t/tt staging vs previous stage2 reads
#pragma unroll
        for (int u = 0; u < 8; u++) {
            int g = tid + u * 256;
            int r = g >> 4, cg = g & 15;
            int dsti = r * 128 + ((cg ^ (r & 7)) << 3);
            const float* s1 = w1 + ((size_t)(fb * 128 + r)) * 128 + cg * 8;
            float4 x = *(const float4*)s1, y = *(const float4*)(s1 + 4);
            short8 v;
            v[0] = f2b(x.x); v[1] = f2b(x.y); v[2] = f2b(x.z); v[3] = f2b(x.w);
            v[4] = f2b(y.x); v[5] = f2b(y.y); v[6] = f2b(y.z); v[7] = f2b(y.w);
            *(short8*)(w1t + dsti) = v;
            const float* s2 = w2 + (size_t)r * 512 + fb * 128 + cg * 8;
            float4 a = *(const float4*)s2, b = *(const float4*)(s2 + 4);
            short8 u2;
            u2[0] = f2b(a.x); u2[1] = f2b(a.y); u2[2] = f2b(a.z); u2[3] = f2b(a.w);
            u2[4] = f2b(b.x); u2[5] = f2b(b.y); u2[6] = f2b(b.z); u2[7] = f2b(b.w);
            *(short8*)(w2t + dsti) = u2;
        }
        __syncthreads();
        // stage 1: a1 = xs @ w1_blk^T
        f32x4 a1[4][4];
#pragma unroll
        for (int i = 0; i < 4; i++)
#pragma unroll
            for (int j = 0; j < 4; j++) a1[i][j] = (f32x4){0.f, 0.f, 0.f, 0.f};
#pragma unroll
        for (int ks = 0; ks < 4; ks++) {
            int cg = ks * 4 + (l >> 4);
            short8 af[4], bf[4];
#pragma unroll
            for (int mi = 0; mi < 4; mi++) {
                int rm = wm * 64 + mi * 16 + (l & 15);
                af[mi] = *(short8*)(xsl + rm * 128 + ((cg ^ (rm & 7)) << 3));
            }
#pragma unroll
            for (int ni = 0; ni < 4; ni++) {
                int rn = wn * 64 + ni * 16 + (l & 15);
                bf[ni] = *(short8*)(w1t + rn * 128 + ((cg ^ (rn & 7)) << 3));
            }
#pragma unroll
            for (int mi = 0; mi < 4; mi++)
#pragma unroll
                for (int ni = 0; ni < 4; ni++)
                    a1[mi][ni] = __builtin_amdgcn_mfma_f32_16x16x32_bf16(af[mi], bf[ni], a1[mi][ni], 0, 0, 0);
        }
        // gelu -> bf16 -> tt (swizzled scatter)
#pragma unroll
        for (int mi = 0; mi < 4; mi++)
#pragma unroll
            for (int ni = 0; ni < 4; ni++)
#pragma unroll
                for (int rr = 0; rr < 4; rr++) {
                    int m = wm * 64 + mi * 16 + (l >> 4) * 4 + rr;
                    int f = wn * 64 + ni * 16 + (l & 15);
                    tt[m * 128 + (f ^ ((m & 7) << 3))] = (short)f2b(gelu_fast(a1[mi][ni][rr]));
                }
        __syncthreads();
        // stage 2: acc2 += t @ w2_blk^T
#pragma unroll
        for (int ks = 0; ks < 4; ks++) {
            int cg = ks * 4 + (l >> 4);
            short8 af[4], bf[4];
#pragma unroll
            for (int mi = 0; mi < 4; mi++) {
                int rm = wm * 64 + mi * 16 + (l & 15);
                af[mi] = *(short8*)(tt + rm * 128 + ((cg ^ (rm & 7)) << 3));
            }
#pragma unroll
            for (int ni = 0; ni < 4; ni++) {
                int rn = wn * 64 + ni * 16 + (l & 15);
                bf[ni] = *(short8*)(w2t + rn * 128 + ((cg ^ (rn & 7)) << 3));
            }
#pragma unroll
            for (int mi = 0; mi < 4; mi++)
#pragma unroll
                for (int ni = 0; ni < 4; ni++)
                    acc2[mi][ni] = __builtin_amdgcn_mfma_f32_16x16x32_bf16(af[mi], bf[ni], acc2[mi][ni], 0, 0, 0);
        }
    }
    __syncthreads();
    float* Dsh = (float*)smem;   // 64KB region over xsl+w1t
#pragma unroll
    for (int mi = 0; mi < 4; mi++)
#pragma unroll
        for (int ni = 0; ni < 4; ni++)
#pragma unroll
            for (int rr = 0; rr < 4; rr++)
                Dsh[(wm * 64 + mi * 16 + (l >> 4) * 4 + rr) * 128 + wn * 64 + ni * 16 + (l & 15)] = acc2[mi][ni][rr];
    __syncthreads();
#pragma unroll
    for (int u = 0; u < 8; u++) {
        int g = tid + u * 256;
        int r = g >> 4, c8 = (g & 15) * 8;
        const float* rp = xs + (row0 + r) * 128 + c8;
        float* op = outp + (row0 + r) * 128 + c8;
        float4 o0, o1;
        o0.x = Dsh[r * 128 + c8 + 0] + rp[0]; o0.y = Dsh[r * 128 + c8 + 1] + rp[1];
        o0.z = Dsh[r * 128 + c8 + 2] + rp[2]; o0.w = Dsh[r * 128 + c8 + 3] + rp[3];
        o1.x = Dsh[r * 128 + c8 + 4] + rp[4]; o1.y = Dsh[r * 128 + c8 + 5] + rp[5];
        o1.z = Dsh[r * 128 + c8 + 6] + rp[6]; o1.w = Dsh[r * 128 + c8 + 7] + rp[7];
        *(float4*)op = o0; *(float4*)(op + 4) = o1;
    }
}

// ---------------- Stockham FFT length 4096 in LDS ----------------
__device__ void fft4096(float2* __restrict__ bufA, float2* __restrict__ bufB,
                        const float2* __restrict__ tw, float sgn) {
    float2* cur = bufA; float2* nxt = bufB;
#pragma unroll 1
    for (int t = 0; t < 12; t++) {
        int s = 1 << t;
#pragma unroll
        for (int ii = 0; ii < 8; ii++) {
            int idx = threadIdx.x + (ii << 8);
            int p = idx >> t;
            int q = idx & (s - 1);
            int ia = q + (p << t);
            float2 a = cur[ia];
            float2 b = cur[ia + 2048];
            float2 w = tw[p << t];
            float cs = w.x, sn = w.y * sgn;
            float dx = a.x - b.x, dy = a.y - b.y;
            int ob = q + (p << (t + 1));
            nxt[ob] = make_float2(a.x + b.x, a.y + b.y);
            nxt[ob + s] = make_float2(dx * cs - dy * sn, dx * sn + dy * cs);
        }
        __syncthreads();
        float2* tmpp = cur; cur = nxt; nxt = tmpp;
    }
}

__global__ __launch_bounds__(256) void kfft_fwd(const float* __restrict__ qkT,
                                                float* __restrict__ Pws, int ghalf) {
    __shared__ float2 bufA[4096];
    __shared__ float2 bufB[4096];
    __shared__ float2 tw[2048];
    for (int j = threadIdx.x; j < 2048; j += 256) {
        float sn, cs;
        sincosf(1.5339807878856412e-3f * (float)j, &sn, &cs);
        tw[j] = make_float2(cs, sn);
    }
    int b = blockIdx.x >> 3;
    int gl = blockIdx.x & 7;
    float2 pacc[16];
#pragma unroll
    for (int j = 0; j < 16; j++) pacc[j] = make_float2(0.f, 0.f);
    for (int c8 = 0; c8 < 8; c8++) {
        int c = gl * 8 + c8;
        const float* qrow = qkT + ((size_t)(b * 128 + c)) * 4096;
        const float* krow = qkT + ((size_t)(b * 128 + 64 + c)) * 4096;
        for (int i = threadIdx.x; i < 4096; i += 256)
            bufA[i] = make_float2(qrow[i], krow[i]);
        __syncthreads();
        fft4096(bufA, bufB, tw, -1.f);
#pragma unroll
        for (int j = 0; j < 16; j++) {
            int f = threadIdx.x + j * 256;
            float2 Zf = bufA[f];
            float2 Zm = bufA[(4096 - f) & 4095];
            float Qre = 0.5f * (Zf.x + Zm.x), Qim = 0.5f * (Zf.y - Zm.y);
            float Kre = 0.5f * (Zf.y + Zm.y), Kim = -0.5f * (Zf.x - Zm.x);
            pacc[j].x += Qre * Kre + Qim * Kim;
            pacc[j].y += Qim * Kre - Qre * Kim;
        }
        __syncthreads();
    }
    float2* P = (float2*)Pws + (size_t)(b * 16 + ghalf * 8 + gl) * 4096;
#pragma unroll
    for (int j = 0; j < 16; j++) { int f = threadIdx.x + j * 256; P[f] = pacc[j]; }
}

__global__ __launch_bounds__(256) void kfft_inv(const float* __restrict__ Pws,
                                                float* __restrict__ meanv) {
    __shared__ float2 bufA[4096];
    __shared__ float2 bufB[4096];
    __shared__ float2 tw[2048];
    for (int j = threadIdx.x; j < 2048; j += 256) {
        float sn, cs;
        sincosf(1.5339807878856412e-3f * (float)j, &sn, &cs);
        tw[j] = make_float2(cs, sn);
    }
    int b = blockIdx.x;
    const float2* P = (const float2*)Pws + (size_t)b * 16 * 4096;
    for (int i = threadIdx.x; i < 4096; i += 256) {
        float2 s = make_float2(0.f, 0.f);
#pragma unroll
        for (int gg = 0; gg < 16; gg++) { float2 v = P[gg * 4096 + i]; s.x += v.x; s.y += v.y; }
        bufA[i] = s;
    }
    __syncthreads();
    fft4096(bufA, bufB, tw, 1.f);
    const float scale = 1.0f / (4096.0f * 128.0f);
    for (int i = threadIdx.x; i < 4096; i += 256)
        meanv[b * 4096 + i] = bufA[i].x * scale;
}

// ---------------- top-8 + per-batch softmax ----------------
__global__ __launch_bounds__(256) void ktopk(const float* __restrict__ meanv,
                                             int* __restrict__ idxout,
                                             float* __restrict__ tc) {
    __shared__ float cm[4096];
    __shared__ float rv[256];
    __shared__ int ri[256];
    __shared__ int sidx[8];
    for (int c = threadIdx.x; c < 4096; c += 256) {
        float s = 0.f;
        for (int b = 0; b < 32; b++) s += meanv[b * 4096 + c];
        cm[c] = s;
    }
    __syncthreads();
    for (int it = 0; it < 8; it++) {
        float bv = -1e30f; int bi = 0;
        for (int c = threadIdx.x; c < 4096; c += 256) {
            float v = cm[c];
            if (v > bv) { bv = v; bi = c; }
        }
        rv[threadIdx.x] = bv; ri[threadIdx.x] = bi;
        __syncthreads();
        for (int off = 128; off > 0; off >>= 1) {
            if (threadIdx.x < off) {
                float v2 = rv[threadIdx.x + off]; int i2 = ri[threadIdx.x + off];
                if (v2 > rv[threadIdx.x] || (v2 == rv[threadIdx.x] && i2 < ri[threadIdx.x])) {
                    rv[threadIdx.x] = v2; ri[threadIdx.x] = i2;
                }
            }
            __syncthreads();
        }
        if (threadIdx.x == 0) { sidx[it] = ri[0]; idxout[it] = ri[0]; cm[ri[0]] = -1e30f; }
        __syncthreads();
    }
    if (threadIdx.x < 32) {
        int b = threadIdx.x;
        float w[8]; float mx = -1e30f;
#pragma unroll
        for (int i = 0; i < 8; i++) { w[i] = meanv[b * 4096 + sidx[i]]; mx = fmaxf(mx, w[i]); }
        float s = 0.f;
#pragma unroll
        for (int i = 0; i < 8; i++) { w[i] = expf(w[i] - mx); s += w[i]; }
#pragma unroll
        for (int i = 0; i < 8; i++) tc[b * 8 + i] = w[i] / s;
    }
}

// ---------------- aggregation over 8 lags (bf16 in/out) ----------------
__global__ __launch_bounds__(256) void kagg(const unsigned short* __restrict__ v,
                                            const float* __restrict__ tc,
                                            const int* __restrict__ idx,
                                            unsigned short* __restrict__ o) {
    int t = blockIdx.x * 256 + threadIdx.x;          // 2.1M groups of 8
    int c8 = (t & 15) * 8; int l = (t >> 4) & 4095; int b = t >> 16;
    float acc[8];
#pragma unroll
    for (int j = 0; j < 8; j++) acc[j] = 0.f;
#pragma unroll
    for (int i = 0; i < 8; i++) {
        int lr = (l + idx[i]) & 4095;
        float wgt = tc[b * 8 + i];
        short8 vv = *(const short8*)&v[((size_t)(b * 4096 + lr)) * 128 + c8];
#pragma unroll
        for (int j = 0; j < 8; j++) acc[j] += wgt * b2f((unsigned short)vv[j]);
    }
    short8 ov;
#pragma unroll
    for (int j = 0; j < 8; j++) ov[j] = (short)f2b(acc[j]);
    *(short8*)&o[((size_t)(b * 4096 + l)) * 128 + c8] = ov;
}

// ---------------- series decomp (rolling window): out = in - movavg25(in) ----------------
__global__ __launch_bounds__(256) void kdecomp(const float* __restrict__ in,
                                               float* __restrict__ outp) {
    int b = blockIdx.x >> 4; int ch = blockIdx.x & 15;
    int s = threadIdx.x >> 7; int d = threadIdx.x & 127;
    int l0 = ch * 256 + s * 128;
    const float* base = in + ((size_t)b * 4096) * 128 + d;
    float* obase = outp + ((size_t)b * 4096) * 128 + d;
    float S = 0.f;
#pragma unroll
    for (int j = -12; j <= 12; j++) {
        int lj = l0 + j;
        lj = lj < 0 ? 0 : (lj > 4095 ? 4095 : lj);
        S += base[(size_t)lj * 128];
    }
    for (int st = 0; st < 128; st++) {
        int l = l0 + st;
        float c = base[(size_t)l * 128];
        obase[(size_t)l * 128] = c - S * (1.0f / 25.0f);
        int ln = l + 13 > 4095 ? 4095 : l + 13;
        int lo = l - 12 < 0 ? 0 : l - 12;
        S += base[(size_t)ln * 128] - base[(size_t)lo * 128];
    }
}

// ---------------- layernorm over d (in place) ----------------
__global__ __launch_bounds__(256) void kln(float* __restrict__ h,
                                           const float* __restrict__ g,
                                           const float* __restrict__ bb) {
    int wave = threadIdx.x >> 6; int lane = threadIdx.x & 63;
    size_t row = (size_t)blockIdx.x * 4 + wave;
    float* p = h + row * 128;
    float v0 = p[lane], v1 = p[lane + 64];
    float s = v0 + v1, s2 = v0 * v0 + v1 * v1;
#pragma unroll
    for (int off = 32; off; off >>= 1) { s += __shfl_down(s, off); s2 += __shfl_down(s2, off); }
    s = __shfl(s, 0); s2 = __shfl(s2, 0);
    float mu = s * (1.f / 128.f);
    float var = s2 * (1.f / 128.f) - mu * mu;
    float inv = rsqrtf(var + 1e-5f);
    p[lane] = (v0 - mu) * inv * g[lane] + bb[lane];
    p[lane + 64] = (v1 - mu) * inv * g[lane + 64] + bb[lane + 64];
}

__global__ __launch_bounds__(256) void kpart1(const float* __restrict__ h,
                                              float* __restrict__ part) {
    int b = blockIdx.x >> 3, sl = blockIdx.x & 7;
    int d = threadIdx.x & 127, p = threadIdx.x >> 7;
    const float* base = h + ((size_t)b * 4096 + sl * 512) * 128;
    float acc = 0.f;
    for (int l = p; l < 512; l += 2) acc += base[(size_t)l * 128 + d];
    __shared__ float sh[256];
    sh[threadIdx.x] = acc; __syncthreads();
    if (p == 0) part[(size_t)(b * 8 + sl) * 128 + d] = acc + sh[128 + d];
}

__global__ __launch_bounds__(128) void kpart2(const float* __restrict__ part,
                                              float* __restrict__ outm) {
    int b = blockIdx.x; int d = threadIdx.x;
    float s = 0.f;
#pragma unroll
    for (int q = 0; q < 8; q++) s += part[(size_t)(b * 8 + q) * 128 + d];
    outm[b * 128 + d] = s * (1.f / 4096.f);
}

__global__ __launch_bounds__(256) void kgpart1(const float* __restrict__ h,
                                               const float* __restrict__ msum,
                                               float* __restrict__ part) {
    int b = blockIdx.x >> 3, sl = blockIdx.x & 7;
    int d = threadIdx.x & 127, p = threadIdx.x >> 7;
    const float* base = h + ((size_t)b * 4096 + sl * 512) * 128;
    float m = msum[b * 128 + d];
    float acc = 0.f;
    for (int l = p; l < 512; l += 2) acc += gelu_f(base[(size_t)l * 128 + d] - m);
    __shared__ float sh[256];
    sh[threadIdx.x] = acc; __syncthreads();
    if (p == 0) part[(size_t)(b * 8 + sl) * 128 + d] = acc + sh[128 + d];
}

__global__ __launch_bounds__(256) void khead(const float* __restrict__ gmean,
                                             const float* __restrict__ fc1w,
                                             const float* __restrict__ fc1b,
                                             const float* __restrict__ fc2w,
                                             const float* __restrict__ fc2b,
                                             float* __restrict__ outp) {
    __shared__ float h0[32][128];
    __shared__ float h1[32][128];
    int tid = threadIdx.x;
#pragma unroll
    for (int i = 0; i < 16; i++) {
        int e = tid + i * 256;
        h0[e >> 7][e & 127] = gmean[e];
    }
    __syncthreads();
#pragma unroll
    for (int i = 0; i < 16; i++) {
        int e = tid + i * 256; int b = e >> 7, j = e & 127;
        float s = fc1b[j];
        for (int d = 0; d < 128; d++) s += h0[b][d] * fc1w[j * 128 + d];
        h1[b][j] = fmaxf(s, 0.f);
    }
    __syncthreads();
    if (tid < 160) {
        int b = tid / 5, c2 = tid % 5;
        float s = fc2b[c2];
        for (int j = 0; j < 128; j++) s += h1[b][j] * fc2w[c2 * 128 + j];
        outp[b * 5 + c2] = s;
    }
}

extern "C" void kernel_launch(void* const* d_in, const int* in_sizes, int n_in,
                              void* d_out, int out_size, void* d_ws, size_t ws_size,
                              hipStream_t stream) {
    const float* x_enc  = (const float*)d_in[0];
    const float* emb_w  = (const float*)d_in[1];
    const float* attn_w = (const float*)d_in[2];
    const float* attn_b = (const float*)d_in[3];
    const float* ffn_w1 = (const float*)d_in[4];
    const float* ffn_w2 = (const float*)d_in[5];
    const float* norm_g = (const float*)d_in[6];
    const float* norm_b = (const float*)d_in[7];
    const float* fc1_w  = (const float*)d_in[8];
    const float* fc1_b  = (const float*)d_in[9];
    const float* fc2_w  = (const float*)d_in[10];
    const float* fc2_b  = (const float*)d_in[11];
    float* outp = (float*)d_out;

    float* W = (float*)d_ws;
    const size_t RD = (size_t)BATCH * L_SEQ * DM;       // 16,777,216
    float* buf0  = W;
    float* buf1  = W + RD;
    float* Pws   = W + 2 * RD;                          // 4,194,304 floats
    float* meanv = Pws + (size_t)4194304;               // 131,072
    float* tcb   = meanv + (size_t)131072;              // 256
    int*   idxb  = (int*)(tcb + 256);                   // 64 slots
    float* part  = tcb + 256 + 64;                      // 32,768
    float* msum  = part + 32768;                        // 4,096
    float* gsum  = msum + 4096;                         // 4,096

    kembed<<<65536, 256, 0, stream>>>(x_enc, emb_w, buf0);

    float* H = buf0;
    float* S = buf1;
    for (int l = 0; l < 2; l++) {
        const float* aw = attn_w + (size_t)l * 4 * 128 * 128;
        const float* ab = attn_b + (size_t)l * 4 * 128;
        // q|k proj (f32, transposed) + packed FFT, two 64-ch halves
        for (int half = 0; half < 2; half++) {
            kgemm_qkt<<<dim3(2048, 2), 256, 0, stream>>>(H, aw, ab, half, S);
            kfft_fwd<<<256, 256, 0, stream>>>(S, Pws, half);
        }
        kfft_inv<<<32, 256, 0, stream>>>(Pws, meanv);
        ktopk<<<1, 256, 0, stream>>>(meanv, idxb, tcb);
        // v projection (MFMA, bf16 out) -> Vb aliases S
        unsigned short* Vb = (unsigned short*)S;
        unsigned short* Ab = Vb + RD;
        kgemm_mfma<0, 0><<<1024, 256, 0, stream>>>(H, aw + 2 * 128 * 128, ab + 256, nullptr, Vb);
        // aggregation over top-8 lags
        kagg<<<8192, 256, 0, stream>>>(Vb, tcb, idxb, Ab);
        // o-proj + residual, in place over H
        kgemm_mfma<1, 1><<<1024, 256, 0, stream>>>(Ab, aw + 3 * 128 * 128, ab + 384, H, H);
        // xs = X - movavg(X)
        kdecomp<<<512, 256, 0, stream>>>(H, S);
        // H = xs + ffn(xs)
        kffn_mfma<<<1024, 256, 0, stream>>>(S, ffn_w1 + (size_t)l * 512 * 128,
                                            ffn_w2 + (size_t)l * 128 * 512, H);
        // h' = H - movavg(H)
        kdecomp<<<512, 256, 0, stream>>>(H, S);
        float* t = H; H = S; S = t;
    }

    kln<<<32768, 256, 0, stream>>>(H, norm_g, norm_b);
    kpart1<<<256, 256, 0, stream>>>(H, part);
    kpart2<<<32, 128, 0, stream>>>(part, msum);
    kgpart1<<<256, 256, 0, stream>>>(H, msum, part);
    kpart2<<<32, 128, 0, stream>>>(part, gsum);
    khead<<<1, 256, 0, stream>>>(gsum, fc1_w, fc1_b, fc2_w, fc2_b, outp);
}

// Round 4
// 1197.696 us; speedup vs baseline: 3.0986x; 1.6595x over previous
//
#include <hip/hip_runtime.h>
#include <math.h>

#define L_SEQ 4096
#define BATCH 32
#define DM 128

typedef short short8 __attribute__((ext_vector_type(8)));
typedef float f32x4 __attribute__((ext_vector_type(4)));

__device__ __forceinline__ float gelu_f(float x) {
    return 0.5f * x * (1.0f + erff(x * 0.70710678118654752f));
}
__device__ __forceinline__ float gelu_fast(float x) {
    float ax = fabsf(x);
    if (ax < 1.0f) {
        float z = x * 0.70710678118654752f;
        float z2 = z * z;
        float p = 1.0f + z2 * (-0.333333333f + z2 * (0.1f + z2 * (-0.0238095238f +
                  z2 * (4.62962963e-3f + z2 * (-7.57575758e-4f)))));
        return 0.5f * x * (1.0f + 1.1283791670955126f * z * p);
    }
    return 0.5f * x * (1.0f + erff(x * 0.70710678118654752f));
}
__device__ __forceinline__ unsigned short f2b(float f) {
    unsigned u = __float_as_uint(f);
    u += 0x7fffu + ((u >> 16) & 1u);
    return (unsigned short)(u >> 16);
}
__device__ __forceinline__ float b2f(unsigned short h) {
    return __uint_as_float(((unsigned)h) << 16);
}

// ---------------- conv1d embedding ----------------
__global__ __launch_bounds__(256) void kembed(const float* __restrict__ x,
                                              const float* __restrict__ w,
                                              float* __restrict__ h) {
    int t = blockIdx.x * 256 + threadIdx.x;
    int o = t & 127; int l = (t >> 7) & 4095; int b = t >> 19;
    int lm = (l + 4095) & 4095, lp = (l + 1) & 4095;
    const float* xr0 = x + ((size_t)b * 4096 + lm) * 12;
    const float* xr1 = x + ((size_t)b * 4096 + l) * 12;
    const float* xr2 = x + ((size_t)b * 4096 + lp) * 12;
    const float* wo = w + o * 36;
    float s = 0.f;
#pragma unroll
    for (int c = 0; c < 12; c++)
        s += wo[c * 3 + 0] * xr0[c] + wo[c * 3 + 1] * xr1[c] + wo[c * 3 + 2] * xr2[c];
    h[t] = s;
}

// ---------------- weight prep: bf16 + pre-swizzled LDS images ----------------
__global__ __launch_bounds__(256) void kprepw(const float* __restrict__ w1,
                                              const float* __restrict__ w2,
                                              unsigned short* __restrict__ w1img,
                                              unsigned short* __restrict__ w2img) {
    int t = blockIdx.x * 256 + threadIdx.x;          // 2 layers * 131072
    int layer = t >> 17; int rem = t & 131071;
    if (rem < 65536) {
        int R = rem >> 7, x = rem & 127;
        int g = x >> 3, j = x & 7;
        int srcc = ((g ^ (R & 7)) << 3) + j;
        w1img[(size_t)layer * 65536 + rem] = f2b(w1[(size_t)layer * 65536 + R * 128 + srcc]);
    } else {
        int r2 = rem - 65536;
        int c = r2 >> 13; int D = (r2 >> 6) & 127; int x = r2 & 63;
        int g = x >> 3, j = x & 7;
        int srcf = c * 64 + ((g ^ (D & 7)) << 3) + j;
        w2img[(size_t)layer * 65536 + r2] = f2b(w2[(size_t)layer * 65536 + D * 512 + srcf]);
    }
}

// ---- q/k projection, bf16x3 MFMA, transposed epilogue: CT[b][y*64+n][l] ----
__global__ __launch_bounds__(256, 2) void kgemm_qk3(const float* __restrict__ A,
                                                    const float* __restrict__ aw,
                                                    const float* __restrict__ ab,
                                                    int half, float* __restrict__ CT) {
    __shared__ __align__(16) char smem[65536];
    short* Ah = (short*)smem;             // [64][128]
    short* Al = (short*)(smem + 16384);
    short* Wh = (short*)(smem + 32768);
    short* Wl = (short*)(smem + 49152);
    int y = blockIdx.y;                   // 0=q, 1=k
    const float* Wp = aw + (size_t)y * 16384 + (size_t)half * 64 * 128;
    const float* bias = ab + y * 128 + half * 64;
    int row0 = blockIdx.x * 64;
    int tid = threadIdx.x;
#pragma unroll
    for (int u = 0; u < 4; u++) {
        int task = tid + u * 256;
        int r = task >> 4, cg = task & 15;
        int dst = r * 128 + ((cg ^ (r & 7)) << 3);
        const float* src = A + ((size_t)(row0 + r)) * 128 + cg * 8;
        float4 xa = *(const float4*)src, ya = *(const float4*)(src + 4);
        float av[8] = {xa.x, xa.y, xa.z, xa.w, ya.x, ya.y, ya.z, ya.w};
        short8 hi, lo;
#pragma unroll
        for (int j = 0; j < 8; j++) {
            unsigned short h = f2b(av[j]);
            hi[j] = (short)h; lo[j] = (short)f2b(av[j] - b2f(h));
        }
        *(short8*)(Ah + dst) = hi; *(short8*)(Al + dst) = lo;
        const float* wsrc = Wp + (size_t)r * 128 + cg * 8;
        float4 xw = *(const float4*)wsrc, yw = *(const float4*)(wsrc + 4);
        float wv[8] = {xw.x, xw.y, xw.z, xw.w, yw.x, yw.y, yw.z, yw.w};
        short8 whi, wlo;
#pragma unroll
        for (int j = 0; j < 8; j++) {
            unsigned short h = f2b(wv[j]);
            whi[j] = (short)h; wlo[j] = (short)f2b(wv[j] - b2f(h));
        }
        *(short8*)(Wh + dst) = whi; *(short8*)(Wl + dst) = wlo;
    }
    __syncthreads();
    int l = tid & 63; int w = tid >> 6; int wm = w >> 1, wn = w & 1;
    f32x4 acc[2][2];
#pragma unroll
    for (int i = 0; i < 2; i++)
#pragma unroll
        for (int j = 0; j < 2; j++) acc[i][j] = (f32x4){0.f, 0.f, 0.f, 0.f};
#pragma unroll
    for (int ks = 0; ks < 4; ks++) {
        int cg = ks * 4 + (l >> 4);
        short8 ah[2], al2[2], bh[2], bl[2];
#pragma unroll
        for (int mi = 0; mi < 2; mi++) {
            int rm = wm * 32 + mi * 16 + (l & 15);
            int off = rm * 128 + ((cg ^ (rm & 7)) << 3);
            ah[mi] = *(short8*)(Ah + off); al2[mi] = *(short8*)(Al + off);
        }
#pragma unroll
        for (int ni = 0; ni < 2; ni++) {
            int rn = wn * 32 + ni * 16 + (l & 15);
            int off = rn * 128 + ((cg ^ (rn & 7)) << 3);
            bh[ni] = *(short8*)(Wh + off); bl[ni] = *(short8*)(Wl + off);
        }
#pragma unroll
        for (int mi = 0; mi < 2; mi++)
#pragma unroll
            for (int ni = 0; ni < 2; ni++) {
                acc[mi][ni] = __builtin_amdgcn_mfma_f32_16x16x32_bf16(ah[mi], bh[ni], acc[mi][ni], 0, 0, 0);
                acc[mi][ni] = __builtin_amdgcn_mfma_f32_16x16x32_bf16(ah[mi], bl[ni], acc[mi][ni], 0, 0, 0);
                acc[mi][ni] = __builtin_amdgcn_mfma_f32_16x16x32_bf16(al2[mi], bh[ni], acc[mi][ni], 0, 0, 0);
            }
    }
    __syncthreads();
    float* Dsh = (float*)smem;            // [64][68]
#pragma unroll
    for (int mi = 0; mi < 2; mi++)
#pragma unroll
        for (int ni = 0; ni < 2; ni++)
#pragma unroll
            for (int rr = 0; rr < 4; rr++) {
                int m = wm * 32 + mi * 16 + (l >> 4) * 4 + rr;
                int n = wn * 32 + ni * 16 + (l & 15);
                Dsh[n * 68 + m] = acc[mi][ni][rr] + bias[n];
            }
    __syncthreads();
    int b = row0 >> 12; int l0 = row0 & 4095;
    int cbase = y * 64;
#pragma unroll
    for (int u = 0; u < 4; u++) {
        int task = tid + u * 256;
        int c = task >> 4, m4 = (task & 15) * 4;
        float4 v = *(float4*)&Dsh[c * 68 + m4];
        *(float4*)&CT[((size_t)(b * 128 + cbase + c)) * 4096 + l0 + m4] = v;
    }
}

// ---------------- MFMA bf16 GEMM (v-proj / o-proj) ----------------
template <int AT, int EPI>
__global__ __launch_bounds__(256, 2) void kgemm_mfma(const void* __restrict__ Ap,
                                                     const float* __restrict__ Wf,
                                                     const float* __restrict__ bias,
                                                     const float* __restrict__ res,
                                                     void* __restrict__ outp) {
    __shared__ __align__(16) char smem[65536];
    short* As = (short*)smem;
    short* Ws = (short*)(smem + 32768);
    int tid = threadIdx.x;
    size_t row0 = (size_t)blockIdx.x * 128;
#pragma unroll
    for (int u = 0; u < 8; u++) {
        int g = tid + u * 256;
        int r = g >> 4, cg = g & 15;
        int dsti = r * 128 + ((cg ^ (r & 7)) << 3);
        short8 v;
        if (AT == 0) {
            const float* src = (const float*)Ap + (row0 + r) * 128 + cg * 8;
            float4 x = *(const float4*)src, y = *(const float4*)(src + 4);
            v[0] = f2b(x.x); v[1] = f2b(x.y); v[2] = f2b(x.z); v[3] = f2b(x.w);
            v[4] = f2b(y.x); v[5] = f2b(y.y); v[6] = f2b(y.z); v[7] = f2b(y.w);
        } else {
            v = *(const short8*)((const short*)Ap + (row0 + r) * 128 + cg * 8);
        }
        *(short8*)(As + dsti) = v;
        const float* ws = Wf + (size_t)r * 128 + cg * 8;
        float4 wx = *(const float4*)ws, wy = *(const float4*)(ws + 4);
        short8 wv;
        wv[0] = f2b(wx.x); wv[1] = f2b(wx.y); wv[2] = f2b(wx.z); wv[3] = f2b(wx.w);
        wv[4] = f2b(wy.x); wv[5] = f2b(wy.y); wv[6] = f2b(wy.z); wv[7] = f2b(wy.w);
        *(short8*)(Ws + dsti) = wv;
    }
    __syncthreads();
    int l = tid & 63; int w = tid >> 6; int wm = w >> 1, wn = w & 1;
    f32x4 acc[4][4];
#pragma unroll
    for (int i = 0; i < 4; i++)
#pragma unroll
        for (int j = 0; j < 4; j++) acc[i][j] = (f32x4){0.f, 0.f, 0.f, 0.f};
#pragma unroll
    for (int ks = 0; ks < 4; ks++) {
        int cg = ks * 4 + (l >> 4);
        short8 af[4], bf[4];
#pragma unroll
        for (int mi = 0; mi < 4; mi++) {
            int rm = wm * 64 + mi * 16 + (l & 15);
            af[mi] = *(short8*)(As + rm * 128 + ((cg ^ (rm & 7)) << 3));
        }
#pragma unroll
        for (int ni = 0; ni < 4; ni++) {
            int rn = wn * 64 + ni * 16 + (l & 15);
            bf[ni] = *(short8*)(Ws + rn * 128 + ((cg ^ (rn & 7)) << 3));
        }
#pragma unroll
        for (int mi = 0; mi < 4; mi++)
#pragma unroll
            for (int ni = 0; ni < 4; ni++)
                acc[mi][ni] = __builtin_amdgcn_mfma_f32_16x16x32_bf16(af[mi], bf[ni], acc[mi][ni], 0, 0, 0);
    }
    __syncthreads();
    float* Dsh = (float*)smem;
#pragma unroll
    for (int mi = 0; mi < 4; mi++)
#pragma unroll
        for (int ni = 0; ni < 4; ni++)
#pragma unroll
            for (int rr = 0; rr < 4; rr++)
                Dsh[(wm * 64 + mi * 16 + (l >> 4) * 4 + rr) * 128 + wn * 64 + ni * 16 + (l & 15)] = acc[mi][ni][rr];
    __syncthreads();
#pragma unroll
    for (int u = 0; u < 8; u++) {
        int g = tid + u * 256;
        int r = g >> 4, c8 = (g & 15) * 8;
        float vv[8];
#pragma unroll
        for (int j = 0; j < 8; j++) vv[j] = Dsh[r * 128 + c8 + j] + bias[c8 + j];
        if (EPI == 1) {
            const float* rp = res + (row0 + r) * 128 + c8;
#pragma unroll
            for (int j = 0; j < 8; j++) vv[j] += rp[j];
            float* op = (float*)outp + (row0 + r) * 128 + c8;
            *(float4*)op = make_float4(vv[0], vv[1], vv[2], vv[3]);
            *(float4*)(op + 4) = make_float4(vv[4], vv[5], vv[6], vv[7]);
        } else {
            short8 ov;
#pragma unroll
            for (int j = 0; j < 8; j++) ov[j] = (short)f2b(vv[j]);
            *(short8*)((short*)outp + (row0 + r) * 128 + c8) = ov;
        }
    }
}

// ---------------- fused MFMA FFN v2: 80 KB LDS, fb=64 chunks ----------------
__global__ __launch_bounds__(256, 2) void kffn_mfma(const float* __restrict__ xs,
                                                    const unsigned short* __restrict__ w1img,
                                                    const unsigned short* __restrict__ w2img,
                                                    float* __restrict__ outp) {
    __shared__ __align__(16) char smem[81920];
    short* xsl = (short*)smem;               // [128][128]  32K
    short* w1t = (short*)(smem + 32768);     // [64][128]   16K
    short* tt  = (short*)(smem + 49152);     // [128][64]   16K
    short* w2t = (short*)(smem + 65536);     // [128][64]   16K
    int tid = threadIdx.x;
    size_t row0 = (size_t)blockIdx.x * 128;
#pragma unroll
    for (int u = 0; u < 8; u++) {
        int g = tid + u * 256;
        int r = g >> 4, cg = g & 15;
        const float* src = xs + (row0 + r) * 128 + cg * 8;
        float4 x = *(const float4*)src, y = *(const float4*)(src + 4);
        short8 v;
        v[0] = f2b(x.x); v[1] = f2b(x.y); v[2] = f2b(x.z); v[3] = f2b(x.w);
        v[4] = f2b(y.x); v[5] = f2b(y.y); v[6] = f2b(y.z); v[7] = f2b(y.w);
        *(short8*)(xsl + r * 128 + ((cg ^ (r & 7)) << 3)) = v;
    }
    int l = tid & 63; int w = tid >> 6; int wm = w >> 1, wn = w & 1;
    f32x4 acc2[4][4];
#pragma unroll
    for (int i = 0; i < 4; i++)
#pragma unroll
        for (int j = 0; j < 4; j++) acc2[i][j] = (f32x4){0.f, 0.f, 0.f, 0.f};
    for (int fb = 0; fb < 8; fb++) {
        __syncthreads();                       // BAR_A
#pragma unroll
        for (int u = 0; u < 4; u++) {
            int task = tid + u * 256;
            int r = task >> 4, cg = task & 15;
            *(short8*)(w1t + r * 128 + cg * 8) =
                *(const short8*)(w1img + ((size_t)(fb * 64 + r)) * 128 + cg * 8);
            int r2 = task >> 3, cg2 = task & 7;
            *(short8*)(w2t + r2 * 64 + cg2 * 8) =
                *(const short8*)(w2img + ((size_t)(fb * 128 + r2)) * 64 + cg2 * 8);
        }
        __syncthreads();                       // BAR_B
        // stage 1: t[128][64] = gelu(xsl @ w1_chunk^T)
        f32x4 a1[4][2];
#pragma unroll
        for (int i = 0; i < 4; i++)
#pragma unroll
            for (int j = 0; j < 2; j++) a1[i][j] = (f32x4){0.f, 0.f, 0.f, 0.f};
#pragma unroll
        for (int ks = 0; ks < 4; ks++) {
            int cg = ks * 4 + (l >> 4);
            short8 af[4], bf[2];
#pragma unroll
            for (int mi = 0; mi < 4; mi++) {
                int rm = wm * 64 + mi * 16 + (l & 15);
                af[mi] = *(short8*)(xsl + rm * 128 + ((cg ^ (rm & 7)) << 3));
            }
#pragma unroll
            for (int ni = 0; ni < 2; ni++) {
                int rn = wn * 32 + ni * 16 + (l & 15);
                bf[ni] = *(short8*)(w1t + rn * 128 + ((cg ^ (rn & 7)) << 3));
            }
#pragma unroll
            for (int mi = 0; mi < 4; mi++)
#pragma unroll
                for (int ni = 0; ni < 2; ni++)
                    a1[mi][ni] = __builtin_amdgcn_mfma_f32_16x16x32_bf16(af[mi], bf[ni], a1[mi][ni], 0, 0, 0);
        }
#pragma unroll
        for (int mi = 0; mi < 4; mi++)
#pragma unroll
            for (int ni = 0; ni < 2; ni++)
#pragma unroll
                for (int rr = 0; rr < 4; rr++) {
                    int m = wm * 64 + mi * 16 + (l >> 4) * 4 + rr;
                    int f = wn * 32 + ni * 16 + (l & 15);
                    tt[m * 64 + (((f >> 3) ^ (m & 7)) << 3) + (f & 7)] = (short)f2b(gelu_fast(a1[mi][ni][rr]));
                }
        __syncthreads();                       // BAR_C
        // stage 2: acc2 += t @ w2_chunk^T  (K=64)
#pragma unroll
        for (int ks = 0; ks < 2; ks++) {
            int cg = ks * 4 + (l >> 4);
            short8 af[4], bf[4];
#pragma unroll
            for (int mi = 0; mi < 4; mi++) {
                int rm = wm * 64 + mi * 16 + (l & 15);
                af[mi] = *(short8*)(tt + rm * 64 + ((cg ^ (rm & 7)) << 3));
            }
#pragma unroll
            for (int ni = 0; ni < 4; ni++) {
                int rn = wn * 64 + ni * 16 + (l & 15);
                bf[ni] = *(short8*)(w2t + rn * 64 + ((cg ^ (rn & 7)) << 3));
            }
#pragma unroll
            for (int mi = 0; mi < 4; mi++)
#pragma unroll
                for (int ni = 0; ni < 4; ni++)
                    acc2[mi][ni] = __builtin_amdgcn_mfma_f32_16x16x32_bf16(af[mi], bf[ni], acc2[mi][ni], 0, 0, 0);
        }
    }
    __syncthreads();
    float* Dsh = (float*)smem;                 // 64 KB over xsl+w1t+tt
#pragma unroll
    for (int mi = 0; mi < 4; mi++)
#pragma unroll
        for (int ni = 0; ni < 4; ni++)
#pragma unroll
            for (int rr = 0; rr < 4; rr++)
                Dsh[(wm * 64 + mi * 16 + (l >> 4) * 4 + rr) * 128 + wn * 64 + ni * 16 + (l & 15)] = acc2[mi][ni][rr];
    __syncthreads();
#pragma unroll
    for (int u = 0; u < 8; u++) {
        int g = tid + u * 256;
        int r = g >> 4, c8 = (g & 15) * 8;
        const float* rp = xs + (row0 + r) * 128 + c8;
        float* op = outp + (row0 + r) * 128 + c8;
        float4 o0, o1;
        o0.x = Dsh[r * 128 + c8 + 0] + rp[0]; o0.y = Dsh[r * 128 + c8 + 1] + rp[1];
        o0.z = Dsh[r * 128 + c8 + 2] + rp[2]; o0.w = Dsh[r * 128 + c8 + 3] + rp[3];
        o1.x = Dsh[r * 128 + c8 + 4] + rp[4]; o1.y = Dsh[r * 128 + c8 + 5] + rp[5];
        o1.z = Dsh[r * 128 + c8 + 6] + rp[6]; o1.w = Dsh[r * 128 + c8 + 7] + rp[7];
        *(float4*)op = o0; *(float4*)(op + 4) = o1;
    }
}

// ---------------- radix-4 Stockham FFT-4096, 1024 threads ----------------
#define FIDX(a) ((a) + ((a) >> 4))

__device__ __forceinline__ float2 twget(const float2* __restrict__ tw, int a, float sgn) {
    float2 T = tw[a & 1023];
    int hi = (a >> 10) & 3;
    float cs = (hi & 1) ? ((hi & 2) ? T.y : -T.y) : ((hi & 2) ? -T.x : T.x);
    float sn = (hi & 1) ? ((hi & 2) ? -T.x : T.x) : ((hi & 2) ? -T.y : T.y);
    return make_float2(cs, sn * sgn);
}

__device__ void fft4096_r4(float2* __restrict__ b0, float2* __restrict__ b1,
                           const float2* __restrict__ tw, float sgn, int tid) {
    float2* cur = b0; float2* nxt = b1;
#pragma unroll
    for (int t = 0; t < 6; t++) {
        int s = 1 << (t << 1);
        int q = tid & (s - 1);
        int ps = tid - q;                       // p*s
        float2 a0 = cur[FIDX(tid)];
        float2 a1 = cur[FIDX(tid + 1024)];
        float2 a2 = cur[FIDX(tid + 2048)];
        float2 a3 = cur[FIDX(tid + 3072)];
        float t0x = a0.x + a2.x, t0y = a0.y + a2.y;
        float t1x = a0.x - a2.x, t1y = a0.y - a2.y;
        float t2x = a1.x + a3.x, t2y = a1.y + a3.y;
        float t3x = a1.x - a3.x, t3y = a1.y - a3.y;
        float it3x = -sgn * t3y, it3y = sgn * t3x;
        float2 A0 = make_float2(t0x + t2x, t0y + t2y);
        float2 A1 = make_float2(t1x + it3x, t1y + it3y);
        float2 A2 = make_float2(t0x - t2x, t0y - t2y);
        float2 A3 = make_float2(t1x - it3x, t1y - it3y);
        int ob = q + (ps << 2);
        nxt[FIDX(ob)] = A0;
        float2 w1 = twget(tw, ps, sgn);
        float2 w2 = twget(tw, ps * 2, sgn);
        float2 w3 = twget(tw, ps * 3, sgn);
        nxt[FIDX(ob + s)] = make_float2(A1.x * w1.x - A1.y * w1.y, A1.x * w1.y + A1.y * w1.x);
        nxt[FIDX(ob + 2 * s)] = make_float2(A2.x * w2.x - A2.y * w2.y, A2.x * w2.y + A2.y * w2.x);
        nxt[FIDX(ob + 3 * s)] = make_float2(A3.x * w3.x - A3.y * w3.y, A3.x * w3.y + A3.y * w3.x);
        __syncthreads();
        float2* tp = cur; cur = nxt; nxt = tp;
    }
}

__global__ __launch_bounds__(1024) void kfft_fwd(const float* __restrict__ qkT,
                                                 float* __restrict__ Pws, int ghalf) {
    __shared__ float2 bufA[4352];
    __shared__ float2 bufB[4352];
    __shared__ float2 tw[1024];
    int tid = threadIdx.x;
    {
        float sn, cs;
        sincosf(1.5339807878856412e-3f * (float)tid, &sn, &cs);
        tw[tid] = make_float2(cs, sn);
    }
    int b = blockIdx.x >> 3;
    int gl = blockIdx.x & 7;
    float2 pacc[4];
#pragma unroll
    for (int j = 0; j < 4; j++) pacc[j] = make_float2(0.f, 0.f);
    for (int c8 = 0; c8 < 8; c8++) {
        int c = gl * 8 + c8;
        const float* qrow = qkT + ((size_t)(b * 128 + c)) * 4096;
        const float* krow = qkT + ((size_t)(b * 128 + 64 + c)) * 4096;
        __syncthreads();
#pragma unroll
        for (int j = 0; j < 4; j++) {
            int i = tid + j * 1024;
            bufA[FIDX(i)] = make_float2(qrow[i], krow[i]);
        }
        __syncthreads();
        fft4096_r4(bufA, bufB, tw, -1.f, tid);
#pragma unroll
        for (int j = 0; j < 4; j++) {
            int f = tid + j * 1024;
            float2 Zf = bufA[FIDX(f)];
            float2 Zm = bufA[FIDX((4096 - f) & 4095)];
            float Qre = 0.5f * (Zf.x + Zm.x), Qim = 0.5f * (Zf.y - Zm.y);
            float Kre = 0.5f * (Zf.y + Zm.y), Kim = -0.5f * (Zf.x - Zm.x);
            pacc[j].x += Qre * Kre + Qim * Kim;
            pacc[j].y += Qim * Kre - Qre * Kim;
        }
    }
    float2* P = (float2*)Pws + (size_t)(b * 16 + ghalf * 8 + gl) * 4096;
#pragma unroll
    for (int j = 0; j < 4; j++) { int f = tid + j * 1024; P[f] = pacc[j]; }
}

__global__ __launch_bounds__(1024) void kfft_inv(const float* __restrict__ Pws,
                                                 float* __restrict__ meanv) {
    __shared__ float2 bufA[4352];
    __shared__ float2 bufB[4352];
    __shared__ float2 tw[1024];
    int tid = threadIdx.x;
    {
        float sn, cs;
        sincosf(1.5339807878856412e-3f * (float)tid, &sn, &cs);
        tw[tid] = make_float2(cs, sn);
    }
    int b = blockIdx.x;
    const float2* P = (const float2*)Pws + (size_t)b * 16 * 4096;
#pragma unroll
    for (int j = 0; j < 4; j++) {
        int i = tid + j * 1024;
        float2 s = make_float2(0.f, 0.f);
#pragma unroll
        for (int gg = 0; gg < 16; gg++) { float2 v = P[gg * 4096 + i]; s.x += v.x; s.y += v.y; }
        bufA[FIDX(i)] = s;
    }
    __syncthreads();
    fft4096_r4(bufA, bufB, tw, 1.f, tid);
    const float scale = 1.0f / (4096.0f * 128.0f);
#pragma unroll
    for (int j = 0; j < 4; j++) {
        int i = tid + j * 1024;
        meanv[b * 4096 + i] = bufA[FIDX(i)].x * scale;
    }
}

// ---------------- top-8 + per-batch softmax ----------------
__global__ __launch_bounds__(256) void ktopk(const float* __restrict__ meanv,
                                             int* __restrict__ idxout,
                                             float* __restrict__ tc) {
    __shared__ float cm[4096];
    __shared__ float rv[256];
    __shared__ int ri[256];
    __shared__ int sidx[8];
    for (int c = threadIdx.x; c < 4096; c += 256) {
        float s = 0.f;
        for (int b = 0; b < 32; b++) s += meanv[b * 4096 + c];
        cm[c] = s;
    }
    __syncthreads();
    for (int it = 0; it < 8; it++) {
        float bv = -1e30f; int bi = 0;
        for (int c = threadIdx.x; c < 4096; c += 256) {
            float v = cm[c];
            if (v > bv) { bv = v; bi = c; }
        }
        rv[threadIdx.x] = bv; ri[threadIdx.x] = bi;
        __syncthreads();
        for (int off = 128; off > 0; off >>= 1) {
            if (threadIdx.x < off) {
                float v2 = rv[threadIdx.x + off]; int i2 = ri[threadIdx.x + off];
                if (v2 > rv[threadIdx.x] || (v2 == rv[threadIdx.x] && i2 < ri[threadIdx.x])) {
                    rv[threadIdx.x] = v2; ri[threadIdx.x] = i2;
                }
            }
            __syncthreads();
        }
        if (threadIdx.x == 0) { sidx[it] = ri[0]; idxout[it] = ri[0]; cm[ri[0]] = -1e30f; }
        __syncthreads();
    }
    if (threadIdx.x < 32) {
        int b = threadIdx.x;
        float w[8]; float mx = -1e30f;
#pragma unroll
        for (int i = 0; i < 8; i++) { w[i] = meanv[b * 4096 + sidx[i]]; mx = fmaxf(mx, w[i]); }
        float s = 0.f;
#pragma unroll
        for (int i = 0; i < 8; i++) { w[i] = expf(w[i] - mx); s += w[i]; }
#pragma unroll
        for (int i = 0; i < 8; i++) tc[b * 8 + i] = w[i] / s;
    }
}

// ---------------- aggregation over 8 lags (bf16) ----------------
__global__ __launch_bounds__(256) void kagg(const unsigned short* __restrict__ v,
                                            const float* __restrict__ tc,
                                            const int* __restrict__ idx,
                                            unsigned short* __restrict__ o) {
    int t = blockIdx.x * 256 + threadIdx.x;
    int c8 = (t & 15) * 8; int l = (t >> 4) & 4095; int b = t >> 16;
    float acc[8];
#pragma unroll
    for (int j = 0; j < 8; j++) acc[j] = 0.f;
#pragma unroll
    for (int i = 0; i < 8; i++) {
        int lr = (l + idx[i]) & 4095;
        float wgt = tc[b * 8 + i];
        short8 vv = *(const short8*)&v[((size_t)(b * 4096 + lr)) * 128 + c8];
#pragma unroll
        for (int j = 0; j < 8; j++) acc[j] += wgt * b2f((unsigned short)vv[j]);
    }
    short8 ov;
#pragma unroll
    for (int j = 0; j < 8; j++) ov[j] = (short)f2b(acc[j]);
    *(short8*)&o[((size_t)(b * 4096 + l)) * 128 + c8] = ov;
}

// ---------------- series decomp (rolling) ----------------
__global__ __launch_bounds__(256) void kdecomp(const float* __restrict__ in,
                                               float* __restrict__ outp) {
    int b = blockIdx.x >> 4; int ch = blockIdx.x & 15;
    int s = threadIdx.x >> 7; int d = threadIdx.x & 127;
    int l0 = ch * 256 + s * 128;
    const float* base = in + ((size_t)b * 4096) * 128 + d;
    float* obase = outp + ((size_t)b * 4096) * 128 + d;
    float S = 0.f;
#pragma unroll
    for (int j = -12; j <= 12; j++) {
        int lj = l0 + j;
        lj = lj < 0 ? 0 : (lj > 4095 ? 4095 : lj);
        S += base[(size_t)lj * 128];
    }
    for (int st = 0; st < 128; st++) {
        int l = l0 + st;
        float c = base[(size_t)l * 128];
        obase[(size_t)l * 128] = c - S * (1.0f / 25.0f);
        int ln = l + 13 > 4095 ? 4095 : l + 13;
        int lo = l - 12 < 0 ? 0 : l - 12;
        S += base[(size_t)ln * 128] - base[(size_t)lo * 128];
    }
}

// ---------------- layernorm + tail ----------------
__global__ __launch_bounds__(256) void kln(float* __restrict__ h,
                                           const float* __restrict__ g,
                                           const float* __restrict__ bb) {
    int wave = threadIdx.x >> 6; int lane = threadIdx.x & 63;
    size_t row = (size_t)blockIdx.x * 4 + wave;
    float* p = h + row * 128;
    float v0 = p[lane], v1 = p[lane + 64];
    float s = v0 + v1, s2 = v0 * v0 + v1 * v1;
#pragma unroll
    for (int off = 32; off; off >>= 1) { s += __shfl_down(s, off); s2 += __shfl_down(s2, off); }
    s = __shfl(s, 0); s2 = __shfl(s2, 0);
    float mu = s * (1.f / 128.f);
    float var = s2 * (1.f / 128.f) - mu * mu;
    float inv = rsqrtf(var + 1e-5f);
    p[lane] = (v0 - mu) * inv * g[lane] + bb[lane];
    p[lane + 64] = (v1 - mu) * inv * g[lane + 64] + bb[lane + 64];
}

__global__ __launch_bounds__(256) void kpart1(const float* __restrict__ h,
                                              float* __restrict__ part) {
    int b = blockIdx.x >> 3, sl = blockIdx.x & 7;
    int d = threadIdx.x & 127, p = threadIdx.x >> 7;
    const float* base = h + ((size_t)b * 4096 + sl * 512) * 128;
    float acc = 0.f;
    for (int l = p; l < 512; l += 2) acc += base[(size_t)l * 128 + d];
    __shared__ float sh[256];
    sh[threadIdx.x] = acc; __syncthreads();
    if (p == 0) part[(size_t)(b * 8 + sl) * 128 + d] = acc + sh[128 + d];
}

__global__ __launch_bounds__(128) void kpart2(const float* __restrict__ part,
                                              float* __restrict__ outm) {
    int b = blockIdx.x; int d = threadIdx.x;
    float s = 0.f;
#pragma unroll
    for (int q = 0; q < 8; q++) s += part[(size_t)(b * 8 + q) * 128 + d];
    outm[b * 128 + d] = s * (1.f / 4096.f);
}

__global__ __launch_bounds__(256) void kgpart1(const float* __restrict__ h,
                                               const float* __restrict__ msum,
                                               float* __restrict__ part) {
    int b = blockIdx.x >> 3, sl = blockIdx.x & 7;
    int d = threadIdx.x & 127, p = threadIdx.x >> 7;
    const float* base = h + ((size_t)b * 4096 + sl * 512) * 128;
    float m = msum[b * 128 + d];
    float acc = 0.f;
    for (int l = p; l < 512; l += 2) acc += gelu_f(base[(size_t)l * 128 + d] - m);
    __shared__ float sh[256];
    sh[threadIdx.x] = acc; __syncthreads();
    if (p == 0) part[(size_t)(b * 8 + sl) * 128 + d] = acc + sh[128 + d];
}

__global__ __launch_bounds__(256) void khead(const float* __restrict__ gmean,
                                             const float* __restrict__ fc1w,
                                             const float* __restrict__ fc1b,
                                             const float* __restrict__ fc2w,
                                             const float* __restrict__ fc2b,
                                             float* __restrict__ outp) {
    __shared__ float h0[32][128];
    __shared__ float h1[32][128];
    int tid = threadIdx.x;
#pragma unroll
    for (int i = 0; i < 16; i++) {
        int e = tid + i * 256;
        h0[e >> 7][e & 127] = gmean[e];
    }
    __syncthreads();
#pragma unroll
    for (int i = 0; i < 16; i++) {
        int e = tid + i * 256; int b = e >> 7, j = e & 127;
        float s = fc1b[j];
        for (int d = 0; d < 128; d++) s += h0[b][d] * fc1w[j * 128 + d];
        h1[b][j] = fmaxf(s, 0.f);
    }
    __syncthreads();
    if (tid < 160) {
        int b = tid / 5, c2 = tid % 5;
        float s = fc2b[c2];
        for (int j = 0; j < 128; j++) s += h1[b][j] * fc2w[c2 * 128 + j];
        outp[b * 5 + c2] = s;
    }
}

extern "C" void kernel_launch(void* const* d_in, const int* in_sizes, int n_in,
                              void* d_out, int out_size, void* d_ws, size_t ws_size,
                              hipStream_t stream) {
    const float* x_enc  = (const float*)d_in[0];
    const float* emb_w  = (const float*)d_in[1];
    const float* attn_w = (const float*)d_in[2];
    const float* attn_b = (const float*)d_in[3];
    const float* ffn_w1 = (const float*)d_in[4];
    const float* ffn_w2 = (const float*)d_in[5];
    const float* norm_g = (const float*)d_in[6];
    const float* norm_b = (const float*)d_in[7];
    const float* fc1_w  = (const float*)d_in[8];
    const float* fc1_b  = (const float*)d_in[9];
    const float* fc2_w  = (const float*)d_in[10];
    const float* fc2_b  = (const float*)d_in[11];
    float* outp = (float*)d_out;

    float* W = (float*)d_ws;
    const size_t RD = (size_t)BATCH * L_SEQ * DM;       // 16,777,216
    float* buf0  = W;
    float* buf1  = W + RD;
    float* Pws   = W + 2 * RD;                          // 4,194,304 f
    float* meanv = Pws + (size_t)4194304;               // 131,072
    float* tcb   = meanv + (size_t)131072;              // 256
    int*   idxb  = (int*)(tcb + 256);                   // 64 slots
    float* part  = tcb + 256 + 64;                      // 32,768
    float* msum  = part + 32768;                        // 4,096
    float* gsum  = msum + 4096;                         // 4,096
    unsigned short* w1img = (unsigned short*)(gsum + 4096);   // 2*65536 shorts
    unsigned short* w2img = w1img + (size_t)2 * 65536;        // 2*65536 shorts

    kembed<<<65536, 256, 0, stream>>>(x_enc, emb_w, buf0);
    kprepw<<<1024, 256, 0, stream>>>(ffn_w1, ffn_w2, w1img, w2img);

    float* H = buf0;
    float* S = buf1;
    for (int l = 0; l < 2; l++) {
        const float* aw = attn_w + (size_t)l * 4 * 128 * 128;
        const float* ab = attn_b + (size_t)l * 4 * 128;
        for (int half = 0; half < 2; half++) {
            kgemm_qk3<<<dim3(2048, 2), 256, 0, stream>>>(H, aw, ab, half, S);
            kfft_fwd<<<256, 1024, 0, stream>>>(S, Pws, half);
        }
        kfft_inv<<<32, 1024, 0, stream>>>(Pws, meanv);
        ktopk<<<1, 256, 0, stream>>>(meanv, idxb, tcb);
        unsigned short* Vb = (unsigned short*)S;
        unsigned short* Ab = Vb + RD;
        kgemm_mfma<0, 0><<<1024, 256, 0, stream>>>(H, aw + 2 * 128 * 128, ab + 256, nullptr, Vb);
        kagg<<<8192, 256, 0, stream>>>(Vb, tcb, idxb, Ab);
        kgemm_mfma<1, 1><<<1024, 256, 0, stream>>>(Ab, aw + 3 * 128 * 128, ab + 384, H, H);
        kdecomp<<<512, 256, 0, stream>>>(H, S);
        kffn_mfma<<<1024, 256, 0, stream>>>(S, w1img + (size_t)l * 65536,
                                            w2img + (size_t)l * 65536, H);
        kdecomp<<<512, 256, 0, stream>>>(H, S);
        float* t = H; H = S; S = t;
    }

    kln<<<32768, 256, 0, stream>>>(H, norm_g, norm_b);
    kpart1<<<256, 256, 0, stream>>>(H, part);
    kpart2<<<32, 128, 0, stream>>>(part, msum);
    kgpart1<<<256, 256, 0, stream>>>(H, msum, part);
    kpart2<<<32, 128, 0, stream>>>(part, gsum);
    khead<<<1, 256, 0, stream>>>(gsum, fc1_w, fc1_b, fc2_w, fc2_b, outp);
}

// Round 5
// 1030.056 us; speedup vs baseline: 3.6029x; 1.1627x over previous
//
#include <hip/hip_runtime.h>
#include <math.h>

#define L_SEQ 4096
#define BATCH 32
#define DM 128

typedef short short8 __attribute__((ext_vector_type(8)));
typedef float f32x4 __attribute__((ext_vector_type(4)));

__device__ __forceinline__ float gelu_f(float x) {
    return 0.5f * x * (1.0f + erff(x * 0.70710678118654752f));
}
__device__ __forceinline__ float gelu_fast(float x) {
    float ax = fabsf(x);
    if (ax < 1.0f) {
        float z = x * 0.70710678118654752f;
        float z2 = z * z;
        float p = 1.0f + z2 * (-0.333333333f + z2 * (0.1f + z2 * (-0.0238095238f +
                  z2 * (4.62962963e-3f + z2 * (-7.57575758e-4f)))));
        return 0.5f * x * (1.0f + 1.1283791670955126f * z * p);
    }
    return 0.5f * x * (1.0f + erff(x * 0.70710678118654752f));
}
__device__ __forceinline__ unsigned short f2b(float f) {
    unsigned u = __float_as_uint(f);
    u += 0x7fffu + ((u >> 16) & 1u);
    return (unsigned short)(u >> 16);
}
__device__ __forceinline__ float b2f(unsigned short h) {
    return __uint_as_float(((unsigned)h) << 16);
}

// ---------------- conv1d embedding: LDS-staged, weight-in-register ----------------
// block = (b, 128-l tile); 256 threads: o = tid&127, lh = tid>>7 covers 64 l each.
__global__ __launch_bounds__(256) void kembed(const float* __restrict__ x,
                                              const float* __restrict__ w,
                                              float* __restrict__ h) {
    __shared__ float xs[130][12];
    __shared__ float wsm[128][37];
    int b = blockIdx.x >> 5;
    int lt = blockIdx.x & 31;
    int l0 = lt * 128;
    int tid = threadIdx.x;
    for (int i = tid; i < 130 * 12; i += 256) {
        int r = i / 12, c = i - r * 12;
        int gl = (l0 - 1 + r + 4096) & 4095;
        xs[r][c] = x[((size_t)b * 4096 + gl) * 12 + c];
    }
    for (int i = tid; i < 128 * 36; i += 256) {
        int o = i / 36, j = i - o * 36;
        wsm[o][j] = w[i];
    }
    __syncthreads();
    int o = tid & 127, lh = tid >> 7;
    float wr[36];
#pragma unroll
    for (int j = 0; j < 36; j++) wr[j] = wsm[o][j];
    int base_r = lh * 64;
    float ring[4][12];
#pragma unroll
    for (int c = 0; c < 12; c++) { ring[0][c] = xs[base_r][c]; ring[1][c] = xs[base_r + 1][c]; }
    float* hp = h + ((size_t)b * 4096 + l0 + lh * 64) * 128 + o;
#pragma unroll 4
    for (int st = 0; st < 64; st++) {
        int s0 = st & 3, s1 = (st + 1) & 3, s2 = (st + 2) & 3;
#pragma unroll
        for (int c = 0; c < 12; c++) ring[s2][c] = xs[base_r + st + 2][c];
        float s = 0.f;
#pragma unroll
        for (int c = 0; c < 12; c++)
            s += wr[c * 3 + 0] * ring[s0][c] + wr[c * 3 + 1] * ring[s1][c] + wr[c * 3 + 2] * ring[s2][c];
        hp[(size_t)st * 128] = s;
    }
}

// ---------------- weight prep: bf16 + pre-swizzled LDS images ----------------
__global__ __launch_bounds__(256) void kprepw(const float* __restrict__ w1,
                                              const float* __restrict__ w2,
                                              unsigned short* __restrict__ w1img,
                                              unsigned short* __restrict__ w2img) {
    int t = blockIdx.x * 256 + threadIdx.x;          // 2 layers * 131072
    int layer = t >> 17; int rem = t & 131071;
    if (rem < 65536) {
        int R = rem >> 7, x = rem & 127;
        int g = x >> 3, j = x & 7;
        int srcc = ((g ^ (R & 7)) << 3) + j;
        w1img[(size_t)layer * 65536 + rem] = f2b(w1[(size_t)layer * 65536 + R * 128 + srcc]);
    } else {
        int r2 = rem - 65536;
        int c = r2 >> 13; int D = (r2 >> 6) & 127; int x = r2 & 63;
        int g = x >> 3, j = x & 7;
        int srcf = c * 64 + ((g ^ (D & 7)) << 3) + j;
        w2img[(size_t)layer * 65536 + r2] = f2b(w2[(size_t)layer * 65536 + D * 512 + srcf]);
    }
}

// ---- q/k projection, bf16x3 MFMA, transposed epilogue: CT[b][y*64+n][l] ----
__global__ __launch_bounds__(256, 2) void kgemm_qk3(const float* __restrict__ A,
                                                    const float* __restrict__ aw,
                                                    const float* __restrict__ ab,
                                                    int half, float* __restrict__ CT) {
    __shared__ __align__(16) char smem[65536];
    short* Ah = (short*)smem;             // [64][128]
    short* Al = (short*)(smem + 16384);
    short* Wh = (short*)(smem + 32768);
    short* Wl = (short*)(smem + 49152);
    int y = blockIdx.y;                   // 0=q, 1=k
    const float* Wp = aw + (size_t)y * 16384 + (size_t)half * 64 * 128;
    const float* bias = ab + y * 128 + half * 64;
    int row0 = blockIdx.x * 64;
    int tid = threadIdx.x;
#pragma unroll
    for (int u = 0; u < 4; u++) {
        int task = tid + u * 256;
        int r = task >> 4, cg = task & 15;
        int dst = r * 128 + ((cg ^ (r & 7)) << 3);
        const float* src = A + ((size_t)(row0 + r)) * 128 + cg * 8;
        float4 xa = *(const float4*)src, ya = *(const float4*)(src + 4);
        float av[8] = {xa.x, xa.y, xa.z, xa.w, ya.x, ya.y, ya.z, ya.w};
        short8 hi, lo;
#pragma unroll
        for (int j = 0; j < 8; j++) {
            unsigned short h = f2b(av[j]);
            hi[j] = (short)h; lo[j] = (short)f2b(av[j] - b2f(h));
        }
        *(short8*)(Ah + dst) = hi; *(short8*)(Al + dst) = lo;
        const float* wsrc = Wp + (size_t)r * 128 + cg * 8;
        float4 xw = *(const float4*)wsrc, yw = *(const float4*)(wsrc + 4);
        float wv[8] = {xw.x, xw.y, xw.z, xw.w, yw.x, yw.y, yw.z, yw.w};
        short8 whi, wlo;
#pragma unroll
        for (int j = 0; j < 8; j++) {
            unsigned short h = f2b(wv[j]);
            whi[j] = (short)h; wlo[j] = (short)f2b(wv[j] - b2f(h));
        }
        *(short8*)(Wh + dst) = whi; *(short8*)(Wl + dst) = wlo;
    }
    __syncthreads();
    int l = tid & 63; int w = tid >> 6; int wm = w >> 1, wn = w & 1;
    f32x4 acc[2][2];
#pragma unroll
    for (int i = 0; i < 2; i++)
#pragma unroll
        for (int j = 0; j < 2; j++) acc[i][j] = (f32x4){0.f, 0.f, 0.f, 0.f};
#pragma unroll
    for (int ks = 0; ks < 4; ks++) {
        int cg = ks * 4 + (l >> 4);
        short8 ah[2], al2[2], bh[2], bl[2];
#pragma unroll
        for (int mi = 0; mi < 2; mi++) {
            int rm = wm * 32 + mi * 16 + (l & 15);
            int off = rm * 128 + ((cg ^ (rm & 7)) << 3);
            ah[mi] = *(short8*)(Ah + off); al2[mi] = *(short8*)(Al + off);
        }
#pragma unroll
        for (int ni = 0; ni < 2; ni++) {
            int rn = wn * 32 + ni * 16 + (l & 15);
            int off = rn * 128 + ((cg ^ (rn & 7)) << 3);
            bh[ni] = *(short8*)(Wh + off); bl[ni] = *(short8*)(Wl + off);
        }
#pragma unroll
        for (int mi = 0; mi < 2; mi++)
#pragma unroll
            for (int ni = 0; ni < 2; ni++) {
                acc[mi][ni] = __builtin_amdgcn_mfma_f32_16x16x32_bf16(ah[mi], bh[ni], acc[mi][ni], 0, 0, 0);
                acc[mi][ni] = __builtin_amdgcn_mfma_f32_16x16x32_bf16(ah[mi], bl[ni], acc[mi][ni], 0, 0, 0);
                acc[mi][ni] = __builtin_amdgcn_mfma_f32_16x16x32_bf16(al2[mi], bh[ni], acc[mi][ni], 0, 0, 0);
            }
    }
    __syncthreads();
    float* Dsh = (float*)smem;            // [64][68]
#pragma unroll
    for (int mi = 0; mi < 2; mi++)
#pragma unroll
        for (int ni = 0; ni < 2; ni++)
#pragma unroll
            for (int rr = 0; rr < 4; rr++) {
                int m = wm * 32 + mi * 16 + (l >> 4) * 4 + rr;
                int n = wn * 32 + ni * 16 + (l & 15);
                Dsh[n * 68 + m] = acc[mi][ni][rr] + bias[n];
            }
    __syncthreads();
    int b = row0 >> 12; int l0 = row0 & 4095;
    int cbase = y * 64;
#pragma unroll
    for (int u = 0; u < 4; u++) {
        int task = tid + u * 256;
        int c = task >> 4, m4 = (task & 15) * 4;
        float4 v = *(float4*)&Dsh[c * 68 + m4];
        *(float4*)&CT[((size_t)(b * 128 + cbase + c)) * 4096 + l0 + m4] = v;
    }
}

// ---------------- MFMA bf16 GEMM (v-proj / fused agg+o-proj) ----------------
// AT: 0 = A f32; 1 = A bf16; 2 = A aggregated from bf16 V over top-8 lags.
// EPI: 0 = bf16 out; 1 = f32 out + residual.
template <int AT, int EPI>
__global__ __launch_bounds__(256, 2) void kgemm_mfma(const void* __restrict__ Ap,
                                                     const float* __restrict__ Wf,
                                                     const float* __restrict__ bias,
                                                     const float* __restrict__ res,
                                                     const float* __restrict__ tcb,
                                                     const int* __restrict__ idxb,
                                                     void* __restrict__ outp) {
    __shared__ __align__(16) char smem[65536];
    short* As = (short*)smem;
    short* Ws = (short*)(smem + 32768);
    int tid = threadIdx.x;
    size_t row0 = (size_t)blockIdx.x * 128;
#pragma unroll
    for (int u = 0; u < 8; u++) {
        int g = tid + u * 256;
        int r = g >> 4, cg = g & 15;
        int dsti = r * 128 + ((cg ^ (r & 7)) << 3);
        short8 v;
        if (AT == 0) {
            const float* src = (const float*)Ap + (row0 + r) * 128 + cg * 8;
            float4 x = *(const float4*)src, y = *(const float4*)(src + 4);
            v[0] = f2b(x.x); v[1] = f2b(x.y); v[2] = f2b(x.z); v[3] = f2b(x.w);
            v[4] = f2b(y.x); v[5] = f2b(y.y); v[6] = f2b(y.z); v[7] = f2b(y.w);
        } else if (AT == 1) {
            v = *(const short8*)((const short*)Ap + (row0 + r) * 128 + cg * 8);
        } else {
            const unsigned short* Vb = (const unsigned short*)Ap;
            int b = (int)(row0 >> 12);
            int l0 = (int)(row0 & 4095);
            float accv[8];
#pragma unroll
            for (int j = 0; j < 8; j++) accv[j] = 0.f;
#pragma unroll
            for (int i = 0; i < 8; i++) {
                float wgt = tcb[b * 8 + i];
                int lr = (l0 + r + idxb[i]) & 4095;
                short8 vv = *(const short8*)(Vb + ((size_t)(b * 4096 + lr)) * 128 + cg * 8);
#pragma unroll
                for (int j = 0; j < 8; j++) accv[j] += wgt * b2f((unsigned short)vv[j]);
            }
#pragma unroll
            for (int j = 0; j < 8; j++) v[j] = (short)f2b(accv[j]);
        }
        *(short8*)(As + dsti) = v;
        const float* ws = Wf + (size_t)r * 128 + cg * 8;
        float4 wx = *(const float4*)ws, wy = *(const float4*)(ws + 4);
        short8 wv;
        wv[0] = f2b(wx.x); wv[1] = f2b(wx.y); wv[2] = f2b(wx.z); wv[3] = f2b(wx.w);
        wv[4] = f2b(wy.x); wv[5] = f2b(wy.y); wv[6] = f2b(wy.z); wv[7] = f2b(wy.w);
        *(short8*)(Ws + dsti) = wv;
    }
    __syncthreads();
    int l = tid & 63; int w = tid >> 6; int wm = w >> 1, wn = w & 1;
    f32x4 acc[4][4];
#pragma unroll
    for (int i = 0; i < 4; i++)
#pragma unroll
        for (int j = 0; j < 4; j++) acc[i][j] = (f32x4){0.f, 0.f, 0.f, 0.f};
#pragma unroll
    for (int ks = 0; ks < 4; ks++) {
        int cg = ks * 4 + (l >> 4);
        short8 af[4], bf[4];
#pragma unroll
        for (int mi = 0; mi < 4; mi++) {
            int rm = wm * 64 + mi * 16 + (l & 15);
            af[mi] = *(short8*)(As + rm * 128 + ((cg ^ (rm & 7)) << 3));
        }
#pragma unroll
        for (int ni = 0; ni < 4; ni++) {
            int rn = wn * 64 + ni * 16 + (l & 15);
            bf[ni] = *(short8*)(Ws + rn * 128 + ((cg ^ (rn & 7)) << 3));
        }
#pragma unroll
        for (int mi = 0; mi < 4; mi++)
#pragma unroll
            for (int ni = 0; ni < 4; ni++)
                acc[mi][ni] = __builtin_amdgcn_mfma_f32_16x16x32_bf16(af[mi], bf[ni], acc[mi][ni], 0, 0, 0);
    }
    __syncthreads();
    float* Dsh = (float*)smem;
#pragma unroll
    for (int mi = 0; mi < 4; mi++)
#pragma unroll
        for (int ni = 0; ni < 4; ni++)
#pragma unroll
            for (int rr = 0; rr < 4; rr++)
                Dsh[(wm * 64 + mi * 16 + (l >> 4) * 4 + rr) * 128 + wn * 64 + ni * 16 + (l & 15)] = acc[mi][ni][rr];
    __syncthreads();
#pragma unroll
    for (int u = 0; u < 8; u++) {
        int g = tid + u * 256;
        int r = g >> 4, c8 = (g & 15) * 8;
        float vv[8];
#pragma unroll
        for (int j = 0; j < 8; j++) vv[j] = Dsh[r * 128 + c8 + j] + bias[c8 + j];
        if (EPI == 1) {
            const float* rp = res + (row0 + r) * 128 + c8;
#pragma unroll
            for (int j = 0; j < 8; j++) vv[j] += rp[j];
            float* op = (float*)outp + (row0 + r) * 128 + c8;
            *(float4*)op = make_float4(vv[0], vv[1], vv[2], vv[3]);
            *(float4*)(op + 4) = make_float4(vv[4], vv[5], vv[6], vv[7]);
        } else {
            short8 ov;
#pragma unroll
            for (int j = 0; j < 8; j++) ov[j] = (short)f2b(vv[j]);
            *(short8*)((short*)outp + (row0 + r) * 128 + c8) = ov;
        }
    }
}

// ---------------- fused MFMA FFN: 80 KB LDS, fb=64 chunks ----------------
__global__ __launch_bounds__(256, 2) void kffn_mfma(const float* __restrict__ xs,
                                                    const unsigned short* __restrict__ w1img,
                                                    const unsigned short* __restrict__ w2img,
                                                    float* __restrict__ outp) {
    __shared__ __align__(16) char smem[81920];
    short* xsl = (short*)smem;               // [128][128]  32K
    short* w1t = (short*)(smem + 32768);     // [64][128]   16K
    short* tt  = (short*)(smem + 49152);     // [128][64]   16K
    short* w2t = (short*)(smem + 65536);     // [128][64]   16K
    int tid = threadIdx.x;
    size_t row0 = (size_t)blockIdx.x * 128;
#pragma unroll
    for (int u = 0; u < 8; u++) {
        int g = tid + u * 256;
        int r = g >> 4, cg = g & 15;
        const float* src = xs + (row0 + r) * 128 + cg * 8;
        float4 x = *(const float4*)src, y = *(const float4*)(src + 4);
        short8 v;
        v[0] = f2b(x.x); v[1] = f2b(x.y); v[2] = f2b(x.z); v[3] = f2b(x.w);
        v[4] = f2b(y.x); v[5] = f2b(y.y); v[6] = f2b(y.z); v[7] = f2b(y.w);
        *(short8*)(xsl + r * 128 + ((cg ^ (r & 7)) << 3)) = v;
    }
    int l = tid & 63; int w = tid >> 6; int wm = w >> 1, wn = w & 1;
    f32x4 acc2[4][4];
#pragma unroll
    for (int i = 0; i < 4; i++)
#pragma unroll
        for (int j = 0; j < 4; j++) acc2[i][j] = (f32x4){0.f, 0.f, 0.f, 0.f};
    for (int fb = 0; fb < 8; fb++) {
        __syncthreads();                       // BAR_A
#pragma unroll
        for (int u = 0; u < 4; u++) {
            int task = tid + u * 256;
            int r = task >> 4, cg = task & 15;
            *(short8*)(w1t + r * 128 + cg * 8) =
                *(const short8*)(w1img + ((size_t)(fb * 64 + r)) * 128 + cg * 8);
            int r2 = task >> 3, cg2 = task & 7;
            *(short8*)(w2t + r2 * 64 + cg2 * 8) =
                *(const short8*)(w2img + ((size_t)(fb * 128 + r2)) * 64 + cg2 * 8);
        }
        __syncthreads();                       // BAR_B
        f32x4 a1[4][2];
#pragma unroll
        for (int i = 0; i < 4; i++)
#pragma unroll
            for (int j = 0; j < 2; j++) a1[i][j] = (f32x4){0.f, 0.f, 0.f, 0.f};
#pragma unroll
        for (int ks = 0; ks < 4; ks++) {
            int cg = ks * 4 + (l >> 4);
            short8 af[4], bf[2];
#pragma unroll
            for (int mi = 0; mi < 4; mi++) {
                int rm = wm * 64 + mi * 16 + (l & 15);
                af[mi] = *(short8*)(xsl + rm * 128 + ((cg ^ (rm & 7)) << 3));
            }
#pragma unroll
            for (int ni = 0; ni < 2; ni++) {
                int rn = wn * 32 + ni * 16 + (l & 15);
                bf[ni] = *(short8*)(w1t + rn * 128 + ((cg ^ (rn & 7)) << 3));
            }
#pragma unroll
            for (int mi = 0; mi < 4; mi++)
#pragma unroll
                for (int ni = 0; ni < 2; ni++)
                    a1[mi][ni] = __builtin_amdgcn_mfma_f32_16x16x32_bf16(af[mi], bf[ni], a1[mi][ni], 0, 0, 0);
        }
#pragma unroll
        for (int mi = 0; mi < 4; mi++)
#pragma unroll
            for (int ni = 0; ni < 2; ni++)
#pragma unroll
                for (int rr = 0; rr < 4; rr++) {
                    int m = wm * 64 + mi * 16 + (l >> 4) * 4 + rr;
                    int f = wn * 32 + ni * 16 + (l & 15);
                    tt[m * 64 + (((f >> 3) ^ (m & 7)) << 3) + (f & 7)] = (short)f2b(gelu_fast(a1[mi][ni][rr]));
                }
        __syncthreads();                       // BAR_C
#pragma unroll
        for (int ks = 0; ks < 2; ks++) {
            int cg = ks * 4 + (l >> 4);
            short8 af[4], bf[4];
#pragma unroll
            for (int mi = 0; mi < 4; mi++) {
                int rm = wm * 64 + mi * 16 + (l & 15);
                af[mi] = *(short8*)(tt + rm * 64 + ((cg ^ (rm & 7)) << 3));
            }
#pragma unroll
            for (int ni = 0; ni < 4; ni++) {
                int rn = wn * 64 + ni * 16 + (l & 15);
                bf[ni] = *(short8*)(w2t + rn * 64 + ((cg ^ (rn & 7)) << 3));
            }
#pragma unroll
            for (int mi = 0; mi < 4; mi++)
#pragma unroll
                for (int ni = 0; ni < 4; ni++)
                    acc2[mi][ni] = __builtin_amdgcn_mfma_f32_16x16x32_bf16(af[mi], bf[ni], acc2[mi][ni], 0, 0, 0);
        }
    }
    __syncthreads();
    float* Dsh = (float*)smem;
#pragma unroll
    for (int mi = 0; mi < 4; mi++)
#pragma unroll
        for (int ni = 0; ni < 4; ni++)
#pragma unroll
            for (int rr = 0; rr < 4; rr++)
                Dsh[(wm * 64 + mi * 16 + (l >> 4) * 4 + rr) * 128 + wn * 64 + ni * 16 + (l & 15)] = acc2[mi][ni][rr];
    __syncthreads();
#pragma unroll
    for (int u = 0; u < 8; u++) {
        int g = tid + u * 256;
        int r = g >> 4, c8 = (g & 15) * 8;
        const float* rp = xs + (row0 + r) * 128 + c8;
        float* op = outp + (row0 + r) * 128 + c8;
        float4 o0, o1;
        o0.x = Dsh[r * 128 + c8 + 0] + rp[0]; o0.y = Dsh[r * 128 + c8 + 1] + rp[1];
        o0.z = Dsh[r * 128 + c8 + 2] + rp[2]; o0.w = Dsh[r * 128 + c8 + 3] + rp[3];
        o1.x = Dsh[r * 128 + c8 + 4] + rp[4]; o1.y = Dsh[r * 128 + c8 + 5] + rp[5];
        o1.z = Dsh[r * 128 + c8 + 6] + rp[6]; o1.w = Dsh[r * 128 + c8 + 7] + rp[7];
        *(float4*)op = o0; *(float4*)(op + 4) = o1;
    }
}

// ---------------- radix-4 Stockham FFT-4096, 1024 threads ----------------
#define FIDX(a) ((a) + ((a) >> 4))

__device__ __forceinline__ float2 twget(const float2* __restrict__ tw, int a, float sgn) {
    float2 T = tw[a & 1023];
    int hi = (a >> 10) & 3;
    float cs = (hi & 1) ? ((hi & 2) ? T.y : -T.y) : ((hi & 2) ? -T.x : T.x);
    float sn = (hi & 1) ? ((hi & 2) ? -T.x : T.x) : ((hi & 2) ? -T.y : T.y);
    return make_float2(cs, sn * sgn);
}

__device__ void fft4096_r4(float2* __restrict__ b0, float2* __restrict__ b1,
                           const float2* __restrict__ tw, float sgn, int tid) {
    float2* cur = b0; float2* nxt = b1;
#pragma unroll
    for (int t = 0; t < 6; t++) {
        int s = 1 << (t << 1);
        int q = tid & (s - 1);
        int ps = tid - q;                       // p*s
        float2 a0 = cur[FIDX(tid)];
        float2 a1 = cur[FIDX(tid + 1024)];
        float2 a2 = cur[FIDX(tid + 2048)];
        float2 a3 = cur[FIDX(tid + 3072)];
        float t0x = a0.x + a2.x, t0y = a0.y + a2.y;
        float t1x = a0.x - a2.x, t1y = a0.y - a2.y;
        float t2x = a1.x + a3.x, t2y = a1.y + a3.y;
        float t3x = a1.x - a3.x, t3y = a1.y - a3.y;
        float it3x = -sgn * t3y, it3y = sgn * t3x;
        float2 A0 = make_float2(t0x + t2x, t0y + t2y);
        float2 A1 = make_float2(t1x + it3x, t1y + it3y);
        float2 A2 = make_float2(t0x - t2x, t0y - t2y);
        float2 A3 = make_float2(t1x - it3x, t1y - it3y);
        int ob = q + (ps << 2);
        nxt[FIDX(ob)] = A0;
        float2 w1 = twget(tw, ps, sgn);
        float2 w2 = twget(tw, ps * 2, sgn);
        float2 w3 = twget(tw, ps * 3, sgn);
        nxt[FIDX(ob + s)] = make_float2(A1.x * w1.x - A1.y * w1.y, A1.x * w1.y + A1.y * w1.x);
        nxt[FIDX(ob + 2 * s)] = make_float2(A2.x * w2.x - A2.y * w2.y, A2.x * w2.y + A2.y * w2.x);
        nxt[FIDX(ob + 3 * s)] = make_float2(A3.x * w3.x - A3.y * w3.y, A3.x * w3.y + A3.y * w3.x);
        __syncthreads();
        float2* tp = cur; cur = nxt; nxt = tp;
    }
}

__global__ __launch_bounds__(1024) void kfft_fwd(const float* __restrict__ qkT,
                                                 float* __restrict__ Pws, int ghalf) {
    __shared__ float2 bufA[4352];
    __shared__ float2 bufB[4352];
    __shared__ float2 tw[1024];
    int tid = threadIdx.x;
    {
        float sn, cs;
        sincosf(1.5339807878856412e-3f * (float)tid, &sn, &cs);
        tw[tid] = make_float2(cs, sn);
    }
    int b = blockIdx.x >> 3;
    int gl = blockIdx.x & 7;
    float2 pacc[4];
#pragma unroll
    for (int j = 0; j < 4; j++) pacc[j] = make_float2(0.f, 0.f);
    for (int c8 = 0; c8 < 8; c8++) {
        int c = gl * 8 + c8;
        const float* qrow = qkT + ((size_t)(b * 128 + c)) * 4096;
        const float* krow = qkT + ((size_t)(b * 128 + 64 + c)) * 4096;
        __syncthreads();
#pragma unroll
        for (int j = 0; j < 4; j++) {
            int i = tid + j * 1024;
            bufA[FIDX(i)] = make_float2(qrow[i], krow[i]);
        }
        __syncthreads();
        fft4096_r4(bufA, bufB, tw, -1.f, tid);
#pragma unroll
        for (int j = 0; j < 4; j++) {
            int f = tid + j * 1024;
            float2 Zf = bufA[FIDX(f)];
            float2 Zm = bufA[FIDX((4096 - f) & 4095)];
            float Qre = 0.5f * (Zf.x + Zm.x), Qim = 0.5f * (Zf.y - Zm.y);
            float Kre = 0.5f * (Zf.y + Zm.y), Kim = -0.5f * (Zf.x - Zm.x);
            pacc[j].x += Qre * Kre + Qim * Kim;
            pacc[j].y += Qim * Kre - Qre * Kim;
        }
    }
    float2* P = (float2*)Pws + (size_t)(b * 16 + ghalf * 8 + gl) * 4096;
#pragma unroll
    for (int j = 0; j < 4; j++) { int f = tid + j * 1024; P[f] = pacc[j]; }
}

__global__ __launch_bounds__(1024) void kfft_inv(const float* __restrict__ Pws,
                                                 float* __restrict__ meanv) {
    __shared__ float2 bufA[4352];
    __shared__ float2 bufB[4352];
    __shared__ float2 tw[1024];
    int tid = threadIdx.x;
    {
        float sn, cs;
        sincosf(1.5339807878856412e-3f * (float)tid, &sn, &cs);
        tw[tid] = make_float2(cs, sn);
    }
    int b = blockIdx.x;
    const float2* P = (const float2*)Pws + (size_t)b * 16 * 4096;
#pragma unroll
    for (int j = 0; j < 4; j++) {
        int i = tid + j * 1024;
        float2 s = make_float2(0.f, 0.f);
#pragma unroll
        for (int gg = 0; gg < 16; gg++) { float2 v = P[gg * 4096 + i]; s.x += v.x; s.y += v.y; }
        bufA[FIDX(i)] = s;
    }
    __syncthreads();
    fft4096_r4(bufA, bufB, tw, 1.f, tid);
    const float scale = 1.0f / (4096.0f * 128.0f);
#pragma unroll
    for (int j = 0; j < 4; j++) {
        int i = tid + j * 1024;
        meanv[b * 4096 + i] = bufA[FIDX(i)].x * scale;
    }
}

// ---------------- top-8 + per-batch softmax ----------------
__global__ __launch_bounds__(256) void ktopk(const float* __restrict__ meanv,
                                             int* __restrict__ idxout,
                                             float* __restrict__ tc) {
    __shared__ float cm[4096];
    __shared__ float rv[256];
    __shared__ int ri[256];
    __shared__ int sidx[8];
    for (int c = threadIdx.x; c < 4096; c += 256) {
        float s = 0.f;
        for (int b = 0; b < 32; b++) s += meanv[b * 4096 + c];
        cm[c] = s;
    }
    __syncthreads();
    for (int it = 0; it < 8; it++) {
        float bv = -1e30f; int bi = 0;
        for (int c = threadIdx.x; c < 4096; c += 256) {
            float v = cm[c];
            if (v > bv) { bv = v; bi = c; }
        }
        rv[threadIdx.x] = bv; ri[threadIdx.x] = bi;
        __syncthreads();
        for (int off = 128; off > 0; off >>= 1) {
            if (threadIdx.x < off) {
                float v2 = rv[threadIdx.x + off]; int i2 = ri[threadIdx.x + off];
                if (v2 > rv[threadIdx.x] || (v2 == rv[threadIdx.x] && i2 < ri[threadIdx.x])) {
                    rv[threadIdx.x] = v2; ri[threadIdx.x] = i2;
                }
            }
            __syncthreads();
        }
        if (threadIdx.x == 0) { sidx[it] = ri[0]; idxout[it] = ri[0]; cm[ri[0]] = -1e30f; }
        __syncthreads();
    }
    if (threadIdx.x < 32) {
        int b = threadIdx.x;
        float w[8]; float mx = -1e30f;
#pragma unroll
        for (int i = 0; i < 8; i++) { w[i] = meanv[b * 4096 + sidx[i]]; mx = fmaxf(mx, w[i]); }
        float s = 0.f;
#pragma unroll
        for (int i = 0; i < 8; i++) { w[i] = expf(w[i] - mx); s += w[i]; }
#pragma unroll
        for (int i = 0; i < 8; i++) tc[b * 8 + i] = w[i] / s;
    }
}

// ---------------- series decomp (rolling) ----------------
__global__ __launch_bounds__(256) void kdecomp(const float* __restrict__ in,
                                               float* __restrict__ outp) {
    int b = blockIdx.x >> 4; int ch = blockIdx.x & 15;
    int s = threadIdx.x >> 7; int d = threadIdx.x & 127;
    int l0 = ch * 256 + s * 128;
    const float* base = in + ((size_t)b * 4096) * 128 + d;
    float* obase = outp + ((size_t)b * 4096) * 128 + d;
    float S = 0.f;
#pragma unroll
    for (int j = -12; j <= 12; j++) {
        int lj = l0 + j;
        lj = lj < 0 ? 0 : (lj > 4095 ? 4095 : lj);
        S += base[(size_t)lj * 128];
    }
    for (int st = 0; st < 128; st++) {
        int l = l0 + st;
        float c = base[(size_t)l * 128];
        obase[(size_t)l * 128] = c - S * (1.0f / 25.0f);
        int ln = l + 13 > 4095 ? 4095 : l + 13;
        int lo = l - 12 < 0 ? 0 : l - 12;
        S += base[(size_t)ln * 128] - base[(size_t)lo * 128];
    }
}

// ---------------- layernorm + tail ----------------
__global__ __launch_bounds__(256) void kln(float* __restrict__ h,
                                           const float* __restrict__ g,
                                           const float* __restrict__ bb) {
    int wave = threadIdx.x >> 6; int lane = threadIdx.x & 63;
    size_t row = (size_t)blockIdx.x * 4 + wave;
    float* p = h + row * 128;
    float v0 = p[lane], v1 = p[lane + 64];
    float s = v0 + v1, s2 = v0 * v0 + v1 * v1;
#pragma unroll
    for (int off = 32; off; off >>= 1) { s += __shfl_down(s, off); s2 += __shfl_down(s2, off); }
    s = __shfl(s, 0); s2 = __shfl(s2, 0);
    float mu = s * (1.f / 128.f);
    float var = s2 * (1.f / 128.f) - mu * mu;
    float inv = rsqrtf(var + 1e-5f);
    p[lane] = (v0 - mu) * inv * g[lane] + bb[lane];
    p[lane + 64] = (v1 - mu) * inv * g[lane + 64] + bb[lane + 64];
}

__global__ __launch_bounds__(256) void kpart1(const float* __restrict__ h,
                                              float* __restrict__ part) {
    int b = blockIdx.x >> 3, sl = blockIdx.x & 7;
    int d = threadIdx.x & 127, p = threadIdx.x >> 7;
    const float* base = h + ((size_t)b * 4096 + sl * 512) * 128;
    float acc = 0.f;
    for (int l = p; l < 512; l += 2) acc += base[(size_t)l * 128 + d];
    __shared__ float sh[256];
    sh[threadIdx.x] = acc; __syncthreads();
    if (p == 0) part[(size_t)(b * 8 + sl) * 128 + d] = acc + sh[128 + d];
}

__global__ __launch_bounds__(128) void kpart2(const float* __restrict__ part,
                                              float* __restrict__ outm) {
    int b = blockIdx.x; int d = threadIdx.x;
    float s = 0.f;
#pragma unroll
    for (int q = 0; q < 8; q++) s += part[(size_t)(b * 8 + q) * 128 + d];
    outm[b * 128 + d] = s * (1.f / 4096.f);
}

__global__ __launch_bounds__(256) void kgpart1(const float* __restrict__ h,
                                               const float* __restrict__ msum,
                                               float* __restrict__ part) {
    int b = blockIdx.x >> 3, sl = blockIdx.x & 7;
    int d = threadIdx.x & 127, p = threadIdx.x >> 7;
    const float* base = h + ((size_t)b * 4096 + sl * 512) * 128;
    float m = msum[b * 128 + d];
    float acc = 0.f;
    for (int l = p; l < 512; l += 2) acc += gelu_f(base[(size_t)l * 128 + d] - m);
    __shared__ float sh[256];
    sh[threadIdx.x] = acc; __syncthreads();
    if (p == 0) part[(size_t)(b * 8 + sl) * 128 + d] = acc + sh[128 + d];
}

__global__ __launch_bounds__(256) void khead(const float* __restrict__ gmean,
                                             const float* __restrict__ fc1w,
                                             const float* __restrict__ fc1b,
                                             const float* __restrict__ fc2w,
                                             const float* __restrict__ fc2b,
                                             float* __restrict__ outp) {
    __shared__ float h0[32][128];
    __shared__ float h1[32][128];
    int tid = threadIdx.x;
#pragma unroll
    for (int i = 0; i < 16; i++) {
        int e = tid + i * 256;
        h0[e >> 7][e & 127] = gmean[e];
    }
    __syncthreads();
#pragma unroll
    for (int i = 0; i < 16; i++) {
        int e = tid + i * 256; int b = e >> 7, j = e & 127;
        float s = fc1b[j];
        for (int d = 0; d < 128; d++) s += h0[b][d] * fc1w[j * 128 + d];
        h1[b][j] = fmaxf(s, 0.f);
    }
    __syncthreads();
    if (tid < 160) {
        int b = tid / 5, c2 = tid % 5;
        float s = fc2b[c2];
        for (int j = 0; j < 128; j++) s += h1[b][j] * fc2w[c2 * 128 + j];
        outp[b * 5 + c2] = s;
    }
}

extern "C" void kernel_launch(void* const* d_in, const int* in_sizes, int n_in,
                              void* d_out, int out_size, void* d_ws, size_t ws_size,
                              hipStream_t stream) {
    const float* x_enc  = (const float*)d_in[0];
    const float* emb_w  = (const float*)d_in[1];
    const float* attn_w = (const float*)d_in[2];
    const float* attn_b = (const float*)d_in[3];
    const float* ffn_w1 = (const float*)d_in[4];
    const float* ffn_w2 = (const float*)d_in[5];
    const float* norm_g = (const float*)d_in[6];
    const float* norm_b = (const float*)d_in[7];
    const float* fc1_w  = (const float*)d_in[8];
    const float* fc1_b  = (const float*)d_in[9];
    const float* fc2_w  = (const float*)d_in[10];
    const float* fc2_b  = (const float*)d_in[11];
    float* outp = (float*)d_out;

    float* W = (float*)d_ws;
    const size_t RD = (size_t)BATCH * L_SEQ * DM;       // 16,777,216
    float* buf0  = W;
    float* buf1  = W + RD;
    float* Pws   = W + 2 * RD;                          // 4,194,304 f
    float* meanv = Pws + (size_t)4194304;               // 131,072
    float* tcb   = meanv + (size_t)131072;              // 256
    int*   idxb  = (int*)(tcb + 256);                   // 64 slots
    float* part  = tcb + 256 + 64;                      // 32,768
    float* msum  = part + 32768;                        // 4,096
    float* gsum  = msum + 4096;                         // 4,096
    unsigned short* w1img = (unsigned short*)(gsum + 4096);   // 2*65536 shorts
    unsigned short* w2img = w1img + (size_t)2 * 65536;        // 2*65536 shorts

    kembed<<<1024, 256, 0, stream>>>(x_enc, emb_w, buf0);
    kprepw<<<1024, 256, 0, stream>>>(ffn_w1, ffn_w2, w1img, w2img);

    float* H = buf0;
    float* S = buf1;
    for (int l = 0; l < 2; l++) {
        const float* aw = attn_w + (size_t)l * 4 * 128 * 128;
        const float* ab = attn_b + (size_t)l * 4 * 128;
        for (int half = 0; half < 2; half++) {
            kgemm_qk3<<<dim3(2048, 2), 256, 0, stream>>>(H, aw, ab, half, S);
            kfft_fwd<<<256, 1024, 0, stream>>>(S, Pws, half);
        }
        kfft_inv<<<32, 1024, 0, stream>>>(Pws, meanv);
        ktopk<<<1, 256, 0, stream>>>(meanv, idxb, tcb);
        unsigned short* Vb = (unsigned short*)S;
        // v projection (MFMA, bf16 out)
        kgemm_mfma<0, 0><<<1024, 256, 0, stream>>>(H, aw + 2 * 128 * 128, ab + 256,
                                                   nullptr, nullptr, nullptr, Vb);
        // fused agg + o-proj + residual, in place over H
        kgemm_mfma<2, 1><<<1024, 256, 0, stream>>>(Vb, aw + 3 * 128 * 128, ab + 384,
                                                   H, tcb, idxb, H);
        kdecomp<<<512, 256, 0, stream>>>(H, S);
        kffn_mfma<<<1024, 256, 0, stream>>>(S, w1img + (size_t)l * 65536,
                                            w2img + (size_t)l * 65536, H);
        kdecomp<<<512, 256, 0, stream>>>(H, S);
        float* t = H; H = S; S = t;
    }

    kln<<<32768, 256, 0, stream>>>(H, norm_g, norm_b);
    kpart1<<<256, 256, 0, stream>>>(H, part);
    kpart2<<<32, 128, 0, stream>>>(part, msum);
    kgpart1<<<256, 256, 0, stream>>>(H, msum, part);
    kpart2<<<32, 128, 0, stream>>>(part, gsum);
    khead<<<1, 256, 0, stream>>>(gsum, fc1_w, fc1_b, fc2_w, fc2_b, outp);
}